// Round 1
// baseline (374.684 us; speedup 1.0000x reference)
//
#include <hip/hip_runtime.h>

// NonLocal (flash attention, d=32) + collapsed ASPP, all MFMA bf16 on gfx950.
// Only verified builtin used: mfma_f32_16x16x32_bf16.
// Layout conventions (A: m=lane&15,k=quad*8+j | B: n=lane&15,k=quad*8+j |
//                     D: n=lane&15,m=quad*4+r)

typedef __attribute__((ext_vector_type(8))) short bf16x8;
typedef __attribute__((ext_vector_type(4))) short s16x4;
typedef __attribute__((ext_vector_type(4))) float f32x4;

#define MFMA(a, b, c) __builtin_amdgcn_mfma_f32_16x16x32_bf16((a), (b), (c), 0, 0, 0)

__device__ static inline short f2bf(float f) {
  union { float f; unsigned u; } v; v.f = f;
  unsigned r = v.u + 0x7fffu + ((v.u >> 16) & 1u);
  return (short)(r >> 16);
}
__device__ static inline float bf2f(unsigned short h) {
  union { unsigned u; float f; } v; v.u = ((unsigned)h) << 16;
  return v.f;
}
__device__ static inline s16x4 pk4(f32x4 v) {
  s16x4 r; r.x = f2bf(v.x); r.y = f2bf(v.y); r.z = f2bf(v.z); r.w = f2bf(v.w);
  return r;
}
__device__ static inline f32x4 exp4(f32x4 v) {
  f32x4 r; r.x = __expf(v.x); r.y = __expf(v.y); r.z = __expf(v.z); r.w = __expf(v.w);
  return r;
}

// ---------------- sizes ----------------
// N=4096, CI=32, C=64, padded image 78x78 (halo 7), per-batch z_pad 389376 elems
#define QF_PER_B 131072  // theta/phi/g frag elems per batch
#define ZPB      389376
#define ZPAD_DW  778752  // total z_pad bytes/4

// ---------------- zero ws ----------------
__global__ __launch_bounds__(256) void k_zero(unsigned* zp, float* zmean) {
  int i = blockIdx.x * 256 + threadIdx.x;
  if (i < ZPAD_DW) zp[i] = 0u;
  if (i < 256) zmean[i] = 0.f;
}

// ---------------- weight prep: combined 28-tap kernels + folded Wz ----------------
__global__ __launch_bounds__(64) void k_prep(
    const float* __restrict__ out_w, const float* __restrict__ a1_w,
    const float* __restrict__ a3_w, const float* __restrict__ a5_w,
    const float* __restrict__ a7_w, const float* __restrict__ Wz_w,
    const float* __restrict__ bn_g, const float* __restrict__ Wz_b,
    const float* __restrict__ bn_b,
    unsigned short* __restrict__ Wfrag, unsigned short* __restrict__ WzF,
    float* __restrict__ bias2) {
  int blk = blockIdx.x, lane = threadIdx.x;
  int quad = lane >> 4, l15 = lane & 15;
  if (blk < 112) {
    int tap = blk >> 2, dt = blk & 3;
    const float* w; int goff, ky = 0, kx = 0, ksz = 1;
    if (tap == 0)      { w = a1_w; goff = 64; }
    else if (tap < 10) { w = a3_w; goff = 128; ky = (tap-1)/3;  kx = (tap-1)%3;  ksz = 3; }
    else if (tap < 19) { w = a5_w; goff = 192; ky = (tap-10)/3; kx = (tap-10)%3; ksz = 3; }
    else               { w = a7_w; goff = 256; ky = (tap-19)/3; kx = (tap-19)%3; ksz = 3; }
    int d = dt*16 + l15;
    const float* owr = out_w + d*320 + goff;
    for (int cc = 0; cc < 2; ++cc) {
      bf16x8 v;
      #pragma unroll
      for (int j = 0; j < 8; ++j) {
        int c = cc*32 + quad*8 + j;
        float s = 0.f;
        for (int m = 0; m < 64; ++m)
          s += owr[m] * w[((m*64 + c)*ksz + ky)*ksz + kx];
        v[j] = f2bf(s);
      }
      *(bf16x8*)(Wfrag + (((tap*4 + dt)*2 + cc)*64 + lane)*8) = v;
    }
  } else if (blk < 116) {
    int ct = blk - 112;
    int c = ct*16 + l15;
    float s = bn_g[c] * rsqrtf(1.f + 1e-5f);  // fold BN scale into Wz
    bf16x8 v;
    #pragma unroll
    for (int j = 0; j < 8; ++j) v[j] = f2bf(s * Wz_w[c*32 + quad*8 + j]);
    *(bf16x8*)(WzF + (ct*64 + lane)*8) = v;
  } else {
    float s = bn_g[lane] * rsqrtf(1.f + 1e-5f);
    bias2[lane] = s * Wz_b[lane] + bn_b[lane];
  }
}

// ---------------- QKV 1x1 projections -> pre-swizzled bf16 fragments ----------------
__global__ __launch_bounds__(256) void k_qkv(
    const float* __restrict__ x,
    const float* __restrict__ tw, const float* __restrict__ tb,
    const float* __restrict__ pw, const float* __restrict__ pb,
    const float* __restrict__ gw, const float* __restrict__ gb,
    unsigned short* __restrict__ thetaB, unsigned short* __restrict__ phiB,
    unsigned short* __restrict__ gB) {
  __shared__ float wl[2048];
  __shared__ float bl[32];
  int blk = blockIdx.x;
  int b = blk & 3, pt = (blk >> 2) & 15, proj = blk >> 6;
  const float* w    = proj == 0 ? tw : (proj == 1 ? pw : gw);
  const float* bias = proj == 0 ? tb : (proj == 1 ? pb : gb);
  int tid = threadIdx.x;
  for (int i = tid; i < 2048; i += 256) wl[i] = w[i];
  if (tid < 32) bl[tid] = bias[tid];
  __syncthreads();
  int pix = pt*256 + tid;
  const float* xp = x + b*64*4096 + pix;
  float acc[32];
  #pragma unroll
  for (int ci = 0; ci < 32; ++ci) acc[ci] = bl[ci];
  for (int c = 0; c < 64; ++c) {
    float xv = xp[c*4096];
    #pragma unroll
    for (int ci = 0; ci < 32; ++ci) acc[ci] += wl[ci*64 + c] * xv;
  }
  if (proj < 2) {
    // theta/phi: frag[pix>>4][lane=(pix&15)+16*(ci>>3)][j=ci&7]
    unsigned short* base = (proj == 0 ? thetaB : phiB) + b*QF_PER_B
                           + (pix >> 4)*512 + (pix & 15)*8;
    #pragma unroll
    for (int q = 0; q < 4; ++q) {
      bf16x8 v;
      #pragma unroll
      for (int j = 0; j < 8; ++j) v[j] = f2bf(acc[q*8 + j]);
      *(bf16x8*)(base + q*128) = v;
    }
  } else {
    // g: frag[(pix>>5)*2+(ci>>4)][lane=(ci&15)+16*((pix&31)>>3)][j=pix&7]
    unsigned short* base = gB + b*QF_PER_B + (pix >> 5)*1024
                           + ((pix & 31) >> 3)*128 + (pix & 7);
    #pragma unroll
    for (int ci = 0; ci < 32; ++ci)
      base[(ci >> 4)*512 + (ci & 15)*8] = (unsigned short)f2bf(acc[ci]);
  }
}

// ---------------- flash attention (no-max softmax, K-split=2) ----------------
// block = 1 wave, 32 q-rows, half the key range. Computes S^T = phi@theta so the
// P transpose is ds_write_b64 / ds_read_b128.
__global__ __launch_bounds__(64) void k_attn(
    const unsigned short* __restrict__ thetaB, const unsigned short* __restrict__ phiB,
    const unsigned short* __restrict__ gB, float* __restrict__ part) {
  __shared__ __align__(16) unsigned short plds[1280];
  int blk = blockIdx.x;                       // b(4) x qblk(128) x kh(2)
  int b = blk >> 8, qblk = (blk >> 1) & 127, kh = blk & 1;
  int lane = threadIdx.x, quad = lane >> 4, l15 = lane & 15;
  const bf16x8* thB = (const bf16x8*)(thetaB + b*QF_PER_B);
  const bf16x8* phF = (const bf16x8*)(phiB + b*QF_PER_B);
  const bf16x8* gF  = (const bf16x8*)(gB + b*QF_PER_B);
  bf16x8 th0 = thB[(qblk*2 + 0)*64 + lane];
  bf16x8 th1 = thB[(qblk*2 + 1)*64 + lane];
  const f32x4 z4 = {0.f, 0.f, 0.f, 0.f};
  f32x4 acc00 = z4, acc01 = z4, acc10 = z4, acc11 = z4;  // [qt][tc] of Y^T
  float l0 = 0.f, l1 = 0.f;
  int kt0 = kh*64;
  for (int kt = kt0; kt < kt0 + 64; ++kt) {
    int tbase = kt*128 + lane;
    bf16x8 pf0 = phF[tbase];
    bf16x8 pf1 = phF[tbase + 64];
    bf16x8 gf0 = gF[tbase];
    bf16x8 gf1 = gF[tbase + 64];
    f32x4 s00 = MFMA(pf0, th0, z4);   // S^T[k0..15][q of qt0]
    f32x4 s10 = MFMA(pf1, th0, z4);   // S^T[k16..31]
    f32x4 s01 = MFMA(pf0, th1, z4);
    f32x4 s11 = MFMA(pf1, th1, z4);
    f32x4 p00 = exp4(s00), p10 = exp4(s10), p01 = exp4(s01), p11 = exp4(s11);
    l0 += (p00.x + p00.y + p00.z + p00.w) + (p10.x + p10.y + p10.z + p10.w);
    l1 += (p01.x + p01.y + p01.z + p01.w) + (p11.x + p11.y + p11.z + p11.w);
    // transpose: lane holds (k=quad*4+r, q=l15): pack r -> P_lds[q][k], stride 40
    *(s16x4*)(plds + l15*40 + quad*4)            = pk4(p00);
    *(s16x4*)(plds + l15*40 + quad*4 + 16)       = pk4(p10);
    *(s16x4*)(plds + 640 + l15*40 + quad*4)      = pk4(p01);
    *(s16x4*)(plds + 640 + l15*40 + quad*4 + 16) = pk4(p11);
    bf16x8 pb0 = *(const bf16x8*)(plds + l15*40 + quad*8);        // P^T B-frag qt0
    bf16x8 pb1 = *(const bf16x8*)(plds + 640 + l15*40 + quad*8);  // qt1
    acc00 = MFMA(gf0, pb0, acc00);   // Y^T[ci 0..15][q qt0]
    acc01 = MFMA(gf1, pb0, acc01);   // ci 16..31
    acc10 = MFMA(gf0, pb1, acc10);
    acc11 = MFMA(gf1, pb1, acc11);
  }
  // row-sum over key range: lanes sharing l15 (quads) hold disjoint k
  l0 += __shfl_xor(l0, 16); l0 += __shfl_xor(l0, 32);
  l1 += __shfl_xor(l1, 16); l1 += __shfl_xor(l1, 32);
  float* pp = part + blk*1280 + lane*20;
  *(f32x4*)(pp + 0)  = acc00;
  *(f32x4*)(pp + 4)  = acc01;
  *(f32x4*)(pp + 8)  = acc10;
  *(f32x4*)(pp + 12) = acc11;
  pp[16] = l0; pp[17] = l1;
}

// ---------------- merge K-halves + Wz(+BN folded) + residual -> z_pad bf16 ----------------
__global__ __launch_bounds__(64) void k_merge(
    const float* __restrict__ part, const unsigned short* __restrict__ WzF,
    const float* __restrict__ bias2, const float* __restrict__ x,
    unsigned short* __restrict__ z_pad) {
  __shared__ __align__(16) unsigned short ylds[1280];
  int blk = blockIdx.x;                       // b(4) x qblk(128)
  int b = blk >> 7, qblk = blk & 127;
  int lane = threadIdx.x, quad = lane >> 4, l15 = lane & 15;
  const float* pa = part + (blk*2 + 0)*1280 + lane*20;
  const float* pb = part + (blk*2 + 1)*1280 + lane*20;
  f32x4 a00 = *(const f32x4*)(pa + 0)  + *(const f32x4*)(pb + 0);
  f32x4 a01 = *(const f32x4*)(pa + 4)  + *(const f32x4*)(pb + 4);
  f32x4 a10 = *(const f32x4*)(pa + 8)  + *(const f32x4*)(pb + 8);
  f32x4 a11 = *(const f32x4*)(pa + 12) + *(const f32x4*)(pb + 12);
  float l0 = pa[16] + pb[16], l1 = pa[17] + pb[17];
  float r0 = 1.f / l0, r1 = 1.f / l1;
  a00 *= r0; a01 *= r0; a10 *= r1; a11 *= r1;
  // lane holds (ci=tc*16+quad*4+r, q=qt*16+l15) -> yB[q][ci], stride 40
  *(s16x4*)(ylds + l15*40 + quad*4)             = pk4(a00);
  *(s16x4*)(ylds + l15*40 + 16 + quad*4)        = pk4(a01);
  *(s16x4*)(ylds + (16 + l15)*40 + quad*4)      = pk4(a10);
  *(s16x4*)(ylds + (16 + l15)*40 + 16 + quad*4) = pk4(a11);
  bf16x8 y0 = *(const bf16x8*)(ylds + l15*40 + quad*8);
  bf16x8 y1 = *(const bf16x8*)(ylds + (16 + l15)*40 + quad*8);
  const bf16x8* wzf = (const bf16x8*)WzF;
  const f32x4 z4 = {0.f, 0.f, 0.f, 0.f};
  int q0 = qblk * 32;
  #pragma unroll
  for (int ct = 0; ct < 4; ++ct) {
    bf16x8 wf = wzf[ct*64 + lane];
    f32x4 zq0 = MFMA(wf, y0, z4);
    f32x4 zq1 = MFMA(wf, y1, z4);
    int c0 = ct*16 + quad*4;
    f32x4 b2 = *(const f32x4*)(bias2 + c0);
    #pragma unroll
    for (int qt = 0; qt < 2; ++qt) {
      f32x4 zz = qt ? zq1 : zq0;
      int q = q0 + qt*16 + l15;
      int h = q >> 6, w = q & 63;
      const float* xp = x + (b*64 + c0)*4096 + q;
      s16x4 pkv;
      pkv.x = f2bf(zz.x + b2.x + xp[0]);
      pkv.y = f2bf(zz.y + b2.y + xp[4096]);
      pkv.z = f2bf(zz.z + b2.z + xp[8192]);
      pkv.w = f2bf(zz.w + b2.w + xp[12288]);
      *(s16x4*)(z_pad + b*ZPB + ((h + 7)*78 + (w + 7))*64 + c0) = pkv;
    }
  }
}

// ---------------- channel mean of z (partial + atomic) ----------------
__global__ __launch_bounds__(256) void k_zmean(const unsigned short* __restrict__ z_pad,
                                               float* __restrict__ zmean) {
  __shared__ float red[256];
  int blk = blockIdx.x;                       // b(4) x chunk(8)
  int b = blk >> 3, ch = blk & 7;
  int t = threadIdx.x, c = t & 63, pg = t >> 6;
  const unsigned short* zp = z_pad + b*ZPB;
  float s = 0.f;
  for (int k = 0; k < 128; ++k) {
    int pix = ch*512 + pg*128 + k;
    int row = (pix >> 6) + 7, col = (pix & 63) + 7;
    s += bf2f(zp[(row*78 + col)*64 + c]);
  }
  red[t] = s;
  __syncthreads();
  if (t < 64)
    atomicAdd(zmean + b*64 + c, red[t] + red[64 + t] + red[128 + t] + red[192 + t]);
}

// ---------------- per-(b,d) constant: img branch + all biases ----------------
__global__ __launch_bounds__(64) void k_cb(
    const float* __restrict__ zmean, const float* __restrict__ am_w,
    const float* __restrict__ am_b, const float* __restrict__ out_w,
    const float* __restrict__ out_b, const float* __restrict__ a1_b,
    const float* __restrict__ a3_b, const float* __restrict__ a5_b,
    const float* __restrict__ a7_b, float* __restrict__ c_b) {
  __shared__ float img[64];
  int b = blockIdx.x, d = threadIdx.x;
  float s = am_b[d];
  for (int c = 0; c < 64; ++c)
    s += am_w[d*64 + c] * (zmean[b*64 + c] * (1.f / 4096.f));
  img[d] = s;
  __syncthreads();
  const float* ow = out_w + d*320;
  float r = out_b[d];
  for (int dd = 0; dd < 64; ++dd) r += ow[dd] * img[dd];
  for (int m = 0; m < 64; ++m)
    r += ow[64 + m]*a1_b[m] + ow[128 + m]*a3_b[m] + ow[192 + m]*a5_b[m] + ow[256 + m]*a7_b[m];
  c_b[b*64 + d] = r;
}

// ---------------- collapsed 28-tap ASPP conv (implicit GEMM) ----------------
__global__ __launch_bounds__(64) void k_conv(
    const unsigned short* __restrict__ z_pad, const unsigned short* __restrict__ Wfrag,
    const float* __restrict__ c_b, float* __restrict__ out) {
  static constexpr int DYt[28] = {0, -3,-3,-3,0,0,0,3,3,3,
                                     -5,-5,-5,0,0,0,5,5,5,
                                     -7,-7,-7,0,0,0,7,7,7};
  static constexpr int DXt[28] = {0, -3,0,3,-3,0,3,-3,0,3,
                                     -5,0,5,-5,0,5,-5,0,5,
                                     -7,0,7,-7,0,7,-7,0,7};
  int blk = blockIdx.x;                       // b(4) x h(64) x dt2(2) x wt2(2)
  int b = blk >> 8, h = (blk >> 2) & 63, dt2 = (blk >> 1) & 1, wt2 = blk & 1;
  int lane = threadIdx.x, quad = lane >> 4, l15 = lane & 15;
  const unsigned short* zb = z_pad + b*ZPB + ((h + 7)*78 + 7)*64 + quad*8;
  const bf16x8* wfp = (const bf16x8*)Wfrag + lane;
  int d0 = dt2*2 + 0, d1 = dt2*2 + 1;
  f32x4 cb0 = *(const f32x4*)(c_b + b*64 + d0*16 + quad*4);
  f32x4 cb1 = *(const f32x4*)(c_b + b*64 + d1*16 + quad*4);
  f32x4 acc00 = cb0, acc01 = cb0, acc10 = cb1, acc11 = cb1;
  int col0 = ((wt2*2 + 0)*16 + l15)*64;
  int col1 = ((wt2*2 + 1)*16 + l15)*64;
  #pragma unroll
  for (int tap = 0; tap < 28; ++tap) {
    int toff = (DYt[tap]*78 + DXt[tap])*64;
    const unsigned short* zrow = zb + toff;
    #pragma unroll
    for (int cc = 0; cc < 2; ++cc) {
      bf16x8 zf0 = *(const bf16x8*)(zrow + col0 + cc*32);
      bf16x8 zf1 = *(const bf16x8*)(zrow + col1 + cc*32);
      bf16x8 wf0 = wfp[((tap*4 + d0)*2 + cc)*64];
      bf16x8 wf1 = wfp[((tap*4 + d1)*2 + cc)*64];
      acc00 = MFMA(wf0, zf0, acc00);
      acc01 = MFMA(wf0, zf1, acc01);
      acc10 = MFMA(wf1, zf0, acc10);
      acc11 = MFMA(wf1, zf1, acc11);
    }
  }
  float* ob = out + b*262144 + h*64;
  int w0 = (wt2*2 + 0)*16 + l15, w1 = (wt2*2 + 1)*16 + l15;
  int dd0 = d0*16 + quad*4, dd1 = d1*16 + quad*4;
  ob[(dd0 + 0)*4096 + w0] = acc00.x;
  ob[(dd0 + 1)*4096 + w0] = acc00.y;
  ob[(dd0 + 2)*4096 + w0] = acc00.z;
  ob[(dd0 + 3)*4096 + w0] = acc00.w;
  ob[(dd0 + 0)*4096 + w1] = acc01.x;
  ob[(dd0 + 1)*4096 + w1] = acc01.y;
  ob[(dd0 + 2)*4096 + w1] = acc01.z;
  ob[(dd0 + 3)*4096 + w1] = acc01.w;
  ob[(dd1 + 0)*4096 + w0] = acc10.x;
  ob[(dd1 + 1)*4096 + w0] = acc10.y;
  ob[(dd1 + 2)*4096 + w0] = acc10.z;
  ob[(dd1 + 3)*4096 + w0] = acc10.w;
  ob[(dd1 + 0)*4096 + w1] = acc11.x;
  ob[(dd1 + 1)*4096 + w1] = acc11.y;
  ob[(dd1 + 2)*4096 + w1] = acc11.z;
  ob[(dd1 + 3)*4096 + w1] = acc11.w;
}

extern "C" void kernel_launch(void* const* d_in, const int* in_sizes, int n_in,
                              void* d_out, int out_size, void* d_ws, size_t ws_size,
                              hipStream_t stream) {
  const float* x    = (const float*)d_in[0];
  const float* g_w  = (const float*)d_in[1];
  const float* g_b  = (const float*)d_in[2];
  const float* th_w = (const float*)d_in[3];
  const float* th_b = (const float*)d_in[4];
  const float* ph_w = (const float*)d_in[5];
  const float* ph_b = (const float*)d_in[6];
  const float* Wz_w = (const float*)d_in[7];
  const float* Wz_b = (const float*)d_in[8];
  const float* bn_g = (const float*)d_in[9];
  const float* bn_b = (const float*)d_in[10];
  const float* am_w = (const float*)d_in[11];
  const float* am_b = (const float*)d_in[12];
  const float* a1_w = (const float*)d_in[13];
  const float* a1_b = (const float*)d_in[14];
  const float* a3_w = (const float*)d_in[15];
  const float* a3_b = (const float*)d_in[16];
  const float* a5_w = (const float*)d_in[17];
  const float* a5_b = (const float*)d_in[18];
  const float* a7_w = (const float*)d_in[19];
  const float* a7_b = (const float*)d_in[20];
  const float* out_w = (const float*)d_in[21];
  const float* out_b = (const float*)d_in[22];
  float* out = (float*)d_out;
  char* ws = (char*)d_ws;
  unsigned short* thetaB = (unsigned short*)(ws + 0);
  unsigned short* phiB   = (unsigned short*)(ws + 1048576);
  unsigned short* gB     = (unsigned short*)(ws + 2097152);
  unsigned short* z_pad  = (unsigned short*)(ws + 3145728);
  unsigned short* Wfrag  = (unsigned short*)(ws + 6260736);
  unsigned short* WzF    = (unsigned short*)(ws + 6490112);
  float* zmean           = (float*)(ws + 6494208);
  float* c_b             = (float*)(ws + 6495232);
  float* bias2           = (float*)(ws + 6496256);
  float* part            = (float*)(ws + 6496512);  // + 5,242,880 B

  k_zero<<<dim3(3042), dim3(256), 0, stream>>>((unsigned*)z_pad, zmean);
  k_prep<<<dim3(117), dim3(64), 0, stream>>>(out_w, a1_w, a3_w, a5_w, a7_w,
                                             Wz_w, bn_g, Wz_b, bn_b, Wfrag, WzF, bias2);
  k_qkv<<<dim3(192), dim3(256), 0, stream>>>(x, th_w, th_b, ph_w, ph_b, g_w, g_b,
                                             thetaB, phiB, gB);
  k_attn<<<dim3(1024), dim3(64), 0, stream>>>(thetaB, phiB, gB, part);
  k_merge<<<dim3(512), dim3(64), 0, stream>>>(part, WzF, bias2, x, z_pad);
  k_zmean<<<dim3(32), dim3(256), 0, stream>>>(z_pad, zmean);
  k_cb<<<dim3(4), dim3(64), 0, stream>>>(zmean, am_w, am_b, out_w, out_b,
                                         a1_b, a3_b, a5_b, a7_b, c_b);
  k_conv<<<dim3(1024), dim3(64), 0, stream>>>(z_pad, Wfrag, c_b, out);
}

// Round 2
// 214.284 us; speedup vs baseline: 1.7485x; 1.7485x over previous
//
#include <hip/hip_runtime.h>

// NonLocal (flash attention, d=32) + collapsed ASPP, all MFMA bf16 on gfx950.
// Only verified builtin used: mfma_f32_16x16x32_bf16.
// Layout conventions (A: m=lane&15,k=quad*8+j | B: n=lane&15,k=quad*8+j |
//                     D: n=lane&15,m=quad*4+r)

typedef __attribute__((ext_vector_type(8))) short bf16x8;
typedef __attribute__((ext_vector_type(4))) short s16x4;
typedef __attribute__((ext_vector_type(4))) float f32x4;

#define MFMA(a, b, c) __builtin_amdgcn_mfma_f32_16x16x32_bf16((a), (b), (c), 0, 0, 0)

__device__ static inline short f2bf(float f) {
  union { float f; unsigned u; } v; v.f = f;
  unsigned r = v.u + 0x7fffu + ((v.u >> 16) & 1u);
  return (short)(r >> 16);
}
__device__ static inline float bf2f(unsigned short h) {
  union { unsigned u; float f; } v; v.u = ((unsigned)h) << 16;
  return v.f;
}
__device__ static inline s16x4 pk4(f32x4 v) {
  s16x4 r; r.x = f2bf(v.x); r.y = f2bf(v.y); r.z = f2bf(v.z); r.w = f2bf(v.w);
  return r;
}
__device__ static inline f32x4 exp4(f32x4 v) {
  f32x4 r; r.x = __expf(v.x); r.y = __expf(v.y); r.z = __expf(v.z); r.w = __expf(v.w);
  return r;
}

// ---------------- sizes ----------------
// N=4096, CI=32, C=64, padded image 78x78 (halo 7), per-batch z_pad 389376 elems
#define QF_PER_B 131072  // theta/phi/g frag elems per batch
#define ZPB      389376
#define ZPAD_DW  778752  // total z_pad bytes/4

// ---------------- zero ws ----------------
__global__ __launch_bounds__(256) void k_zero(unsigned* zp, float* zmean) {
  int i = blockIdx.x * 256 + threadIdx.x;
  if (i < ZPAD_DW) zp[i] = 0u;
  if (i < 256) zmean[i] = 0.f;
}

// ---------------- weight prep: combined 28-tap kernels + folded Wz ----------------
// Round 1 was latency-bound (175us, VALUBusy 0.5%): 1024 dependent global loads
// per thread. Now: stage w-slice + out_w-slice in LDS (coalesced), reduce from LDS.
__global__ __launch_bounds__(256) void k_prep(
    const float* __restrict__ out_w, const float* __restrict__ a1_w,
    const float* __restrict__ a3_w, const float* __restrict__ a5_w,
    const float* __restrict__ a7_w, const float* __restrict__ Wz_w,
    const float* __restrict__ bn_g, const float* __restrict__ Wz_b,
    const float* __restrict__ bn_b,
    unsigned short* __restrict__ Wfrag, unsigned short* __restrict__ WzF,
    float* __restrict__ bias2) {
  int blk = blockIdx.x, t = threadIdx.x;
  if (blk < 28) {
    __shared__ float wsm[4096];     // [m][c] for this tap's (ky,kx)
    __shared__ float osm[64 * 65];  // [d][m], stride 65 (kill stride-64 bank conflict)
    int tap = blk;
    const float* w; int goff, kyx = 0, ksq = 9;
    if (tap == 0)      { w = a1_w; goff = 64;  ksq = 1; }
    else if (tap < 10) { w = a3_w; goff = 128; kyx = tap - 1; }
    else if (tap < 19) { w = a5_w; goff = 192; kyx = tap - 10; }
    else               { w = a7_w; goff = 256; kyx = tap - 19; }
    for (int i = t; i < 4096; i += 256) {
      wsm[i] = w[i * ksq + kyx];                  // [m*64+c]
      int d = i >> 6, m = i & 63;
      osm[d * 65 + m] = out_w[d * 320 + goff + m];
    }
    __syncthreads();
    int dt = t >> 6, lane = t & 63, quad = lane >> 4, l15 = lane & 15;
    int d = dt * 16 + l15;
    float acc[16];
    #pragma unroll
    for (int k = 0; k < 16; ++k) acc[k] = 0.f;
    const float* orow = osm + d * 65;
    int c0 = quad * 8;
    for (int m = 0; m < 64; ++m) {
      float o = orow[m];
      const float* wr = wsm + m * 64 + c0;
      #pragma unroll
      for (int cc = 0; cc < 2; ++cc)
        #pragma unroll
        for (int j = 0; j < 8; ++j)
          acc[cc * 8 + j] += o * wr[cc * 32 + j];
    }
    #pragma unroll
    for (int cc = 0; cc < 2; ++cc) {
      bf16x8 v;
      #pragma unroll
      for (int j = 0; j < 8; ++j) v[j] = f2bf(acc[cc * 8 + j]);
      *(bf16x8*)(Wfrag + (((tap * 4 + dt) * 2 + cc) * 64 + lane) * 8) = v;
    }
  } else if (blk == 28) {
    int ct = t >> 6, lane = t & 63, quad = lane >> 4, l15 = lane & 15;
    int c = ct * 16 + l15;
    float s = bn_g[c] * rsqrtf(1.f + 1e-5f);  // fold BN scale into Wz
    bf16x8 v;
    #pragma unroll
    for (int j = 0; j < 8; ++j) v[j] = f2bf(s * Wz_w[c * 32 + quad * 8 + j]);
    *(bf16x8*)(WzF + (ct * 64 + lane) * 8) = v;
  } else if (t < 64) {
    float s = bn_g[t] * rsqrtf(1.f + 1e-5f);
    bias2[t] = s * Wz_b[t] + bn_b[t];
  }
}

// ---------------- QKV 1x1 projections -> pre-swizzled bf16 fragments ----------------
__global__ __launch_bounds__(256) void k_qkv(
    const float* __restrict__ x,
    const float* __restrict__ tw, const float* __restrict__ tb,
    const float* __restrict__ pw, const float* __restrict__ pb,
    const float* __restrict__ gw, const float* __restrict__ gb,
    unsigned short* __restrict__ thetaB, unsigned short* __restrict__ phiB,
    unsigned short* __restrict__ gB) {
  __shared__ float wl[2048];
  __shared__ float bl[32];
  int blk = blockIdx.x;
  int b = blk & 3, pt = (blk >> 2) & 15, proj = blk >> 6;
  const float* w    = proj == 0 ? tw : (proj == 1 ? pw : gw);
  const float* bias = proj == 0 ? tb : (proj == 1 ? pb : gb);
  int tid = threadIdx.x;
  for (int i = tid; i < 2048; i += 256) wl[i] = w[i];
  if (tid < 32) bl[tid] = bias[tid];
  __syncthreads();
  int pix = pt*256 + tid;
  const float* xp = x + b*64*4096 + pix;
  float acc[32];
  #pragma unroll
  for (int ci = 0; ci < 32; ++ci) acc[ci] = bl[ci];
  for (int c = 0; c < 64; ++c) {
    float xv = xp[c*4096];
    #pragma unroll
    for (int ci = 0; ci < 32; ++ci) acc[ci] += wl[ci*64 + c] * xv;
  }
  if (proj < 2) {
    // theta/phi: frag[pix>>4][lane=(pix&15)+16*(ci>>3)][j=ci&7]
    unsigned short* base = (proj == 0 ? thetaB : phiB) + b*QF_PER_B
                           + (pix >> 4)*512 + (pix & 15)*8;
    #pragma unroll
    for (int q = 0; q < 4; ++q) {
      bf16x8 v;
      #pragma unroll
      for (int j = 0; j < 8; ++j) v[j] = f2bf(acc[q*8 + j]);
      *(bf16x8*)(base + q*128) = v;
    }
  } else {
    // g: frag[(pix>>5)*2+(ci>>4)][lane=(ci&15)+16*((pix&31)>>3)][j=pix&7]
    unsigned short* base = gB + b*QF_PER_B + (pix >> 5)*1024
                           + ((pix & 31) >> 3)*128 + (pix & 7);
    #pragma unroll
    for (int ci = 0; ci < 32; ++ci)
      base[(ci >> 4)*512 + (ci & 15)*8] = (unsigned short)f2bf(acc[ci]);
  }
}

// ---------------- flash attention (no-max softmax, K-split=2) ----------------
// block = 1 wave, 32 q-rows, half the key range. Computes S^T = phi@theta so the
// P transpose is ds_write_b64 / ds_read_b128.
__global__ __launch_bounds__(64) void k_attn(
    const unsigned short* __restrict__ thetaB, const unsigned short* __restrict__ phiB,
    const unsigned short* __restrict__ gB, float* __restrict__ part) {
  __shared__ __align__(16) unsigned short plds[1280];
  int blk = blockIdx.x;                       // b(4) x qblk(128) x kh(2)
  int b = blk >> 8, qblk = (blk >> 1) & 127, kh = blk & 1;
  int lane = threadIdx.x, quad = lane >> 4, l15 = lane & 15;
  const bf16x8* thB = (const bf16x8*)(thetaB + b*QF_PER_B);
  const bf16x8* phF = (const bf16x8*)(phiB + b*QF_PER_B);
  const bf16x8* gF  = (const bf16x8*)(gB + b*QF_PER_B);
  bf16x8 th0 = thB[(qblk*2 + 0)*64 + lane];
  bf16x8 th1 = thB[(qblk*2 + 1)*64 + lane];
  const f32x4 z4 = {0.f, 0.f, 0.f, 0.f};
  f32x4 acc00 = z4, acc01 = z4, acc10 = z4, acc11 = z4;  // [qt][tc] of Y^T
  float l0 = 0.f, l1 = 0.f;
  int kt0 = kh*64;
  for (int kt = kt0; kt < kt0 + 64; ++kt) {
    int tbase = kt*128 + lane;
    bf16x8 pf0 = phF[tbase];
    bf16x8 pf1 = phF[tbase + 64];
    bf16x8 gf0 = gF[tbase];
    bf16x8 gf1 = gF[tbase + 64];
    f32x4 s00 = MFMA(pf0, th0, z4);   // S^T[k0..15][q of qt0]
    f32x4 s10 = MFMA(pf1, th0, z4);   // S^T[k16..31]
    f32x4 s01 = MFMA(pf0, th1, z4);
    f32x4 s11 = MFMA(pf1, th1, z4);
    f32x4 p00 = exp4(s00), p10 = exp4(s10), p01 = exp4(s01), p11 = exp4(s11);
    l0 += (p00.x + p00.y + p00.z + p00.w) + (p10.x + p10.y + p10.z + p10.w);
    l1 += (p01.x + p01.y + p01.z + p01.w) + (p11.x + p11.y + p11.z + p11.w);
    // transpose: lane holds (k=quad*4+r, q=l15): pack r -> P_lds[q][k], stride 40
    *(s16x4*)(plds + l15*40 + quad*4)            = pk4(p00);
    *(s16x4*)(plds + l15*40 + quad*4 + 16)       = pk4(p10);
    *(s16x4*)(plds + 640 + l15*40 + quad*4)      = pk4(p01);
    *(s16x4*)(plds + 640 + l15*40 + quad*4 + 16) = pk4(p11);
    bf16x8 pb0 = *(const bf16x8*)(plds + l15*40 + quad*8);        // P^T B-frag qt0
    bf16x8 pb1 = *(const bf16x8*)(plds + 640 + l15*40 + quad*8);  // qt1
    acc00 = MFMA(gf0, pb0, acc00);   // Y^T[ci 0..15][q qt0]
    acc01 = MFMA(gf1, pb0, acc01);   // ci 16..31
    acc10 = MFMA(gf0, pb1, acc10);
    acc11 = MFMA(gf1, pb1, acc11);
  }
  // row-sum over key range: lanes sharing l15 (quads) hold disjoint k
  l0 += __shfl_xor(l0, 16); l0 += __shfl_xor(l0, 32);
  l1 += __shfl_xor(l1, 16); l1 += __shfl_xor(l1, 32);
  float* pp = part + blk*1280 + lane*20;
  *(f32x4*)(pp + 0)  = acc00;
  *(f32x4*)(pp + 4)  = acc01;
  *(f32x4*)(pp + 8)  = acc10;
  *(f32x4*)(pp + 12) = acc11;
  pp[16] = l0; pp[17] = l1;
}

// ---------------- merge K-halves + Wz(+BN folded) + residual -> z_pad bf16 ----------------
__global__ __launch_bounds__(64) void k_merge(
    const float* __restrict__ part, const unsigned short* __restrict__ WzF,
    const float* __restrict__ bias2, const float* __restrict__ x,
    unsigned short* __restrict__ z_pad) {
  __shared__ __align__(16) unsigned short ylds[1280];
  int blk = blockIdx.x;                       // b(4) x qblk(128)
  int b = blk >> 7, qblk = blk & 127;
  int lane = threadIdx.x, quad = lane >> 4, l15 = lane & 15;
  const float* pa = part + (blk*2 + 0)*1280 + lane*20;
  const float* pb = part + (blk*2 + 1)*1280 + lane*20;
  f32x4 a00 = *(const f32x4*)(pa + 0)  + *(const f32x4*)(pb + 0);
  f32x4 a01 = *(const f32x4*)(pa + 4)  + *(const f32x4*)(pb + 4);
  f32x4 a10 = *(const f32x4*)(pa + 8)  + *(const f32x4*)(pb + 8);
  f32x4 a11 = *(const f32x4*)(pa + 12) + *(const f32x4*)(pb + 12);
  float l0 = pa[16] + pb[16], l1 = pa[17] + pb[17];
  float r0 = 1.f / l0, r1 = 1.f / l1;
  a00 *= r0; a01 *= r0; a10 *= r1; a11 *= r1;
  // lane holds (ci=tc*16+quad*4+r, q=qt*16+l15) -> yB[q][ci], stride 40
  *(s16x4*)(ylds + l15*40 + quad*4)             = pk4(a00);
  *(s16x4*)(ylds + l15*40 + 16 + quad*4)        = pk4(a01);
  *(s16x4*)(ylds + (16 + l15)*40 + quad*4)      = pk4(a10);
  *(s16x4*)(ylds + (16 + l15)*40 + 16 + quad*4) = pk4(a11);
  bf16x8 y0 = *(const bf16x8*)(ylds + l15*40 + quad*8);
  bf16x8 y1 = *(const bf16x8*)(ylds + (16 + l15)*40 + quad*8);
  const bf16x8* wzf = (const bf16x8*)WzF;
  const f32x4 z4 = {0.f, 0.f, 0.f, 0.f};
  int q0 = qblk * 32;
  #pragma unroll
  for (int ct = 0; ct < 4; ++ct) {
    bf16x8 wf = wzf[ct*64 + lane];
    f32x4 zq0 = MFMA(wf, y0, z4);
    f32x4 zq1 = MFMA(wf, y1, z4);
    int c0 = ct*16 + quad*4;
    f32x4 b2 = *(const f32x4*)(bias2 + c0);
    #pragma unroll
    for (int qt = 0; qt < 2; ++qt) {
      f32x4 zz = qt ? zq1 : zq0;
      int q = q0 + qt*16 + l15;
      int h = q >> 6, w = q & 63;
      const float* xp = x + (b*64 + c0)*4096 + q;
      s16x4 pkv;
      pkv.x = f2bf(zz.x + b2.x + xp[0]);
      pkv.y = f2bf(zz.y + b2.y + xp[4096]);
      pkv.z = f2bf(zz.z + b2.z + xp[8192]);
      pkv.w = f2bf(zz.w + b2.w + xp[12288]);
      *(s16x4*)(z_pad + b*ZPB + ((h + 7)*78 + (w + 7))*64 + c0) = pkv;
    }
  }
}

// ---------------- channel mean of z (partial + atomic) ----------------
__global__ __launch_bounds__(256) void k_zmean(const unsigned short* __restrict__ z_pad,
                                               float* __restrict__ zmean) {
  __shared__ float red[256];
  int blk = blockIdx.x;                       // b(4) x chunk(8)
  int b = blk >> 3, ch = blk & 7;
  int t = threadIdx.x, c = t & 63, pg = t >> 6;
  const unsigned short* zp = z_pad + b*ZPB;
  float s = 0.f;
  for (int k = 0; k < 128; ++k) {
    int pix = ch*512 + pg*128 + k;
    int row = (pix >> 6) + 7, col = (pix & 63) + 7;
    s += bf2f(zp[(row*78 + col)*64 + c]);
  }
  red[t] = s;
  __syncthreads();
  if (t < 64)
    atomicAdd(zmean + b*64 + c, red[t] + red[64 + t] + red[128 + t] + red[192 + t]);
}

// ---------------- per-(b,d) constant: img branch + all biases ----------------
__global__ __launch_bounds__(64) void k_cb(
    const float* __restrict__ zmean, const float* __restrict__ am_w,
    const float* __restrict__ am_b, const float* __restrict__ out_w,
    const float* __restrict__ out_b, const float* __restrict__ a1_b,
    const float* __restrict__ a3_b, const float* __restrict__ a5_b,
    const float* __restrict__ a7_b, float* __restrict__ c_b) {
  __shared__ float img[64];
  int b = blockIdx.x, d = threadIdx.x;
  float s = am_b[d];
  for (int c = 0; c < 64; ++c)
    s += am_w[d*64 + c] * (zmean[b*64 + c] * (1.f / 4096.f));
  img[d] = s;
  __syncthreads();
  const float* ow = out_w + d*320;
  float r = out_b[d];
  for (int dd = 0; dd < 64; ++dd) r += ow[dd] * img[dd];
  for (int m = 0; m < 64; ++m)
    r += ow[64 + m]*a1_b[m] + ow[128 + m]*a3_b[m] + ow[192 + m]*a5_b[m] + ow[256 + m]*a7_b[m];
  c_b[b*64 + d] = r;
}

// ---------------- collapsed 28-tap ASPP conv (implicit GEMM) ----------------
__global__ __launch_bounds__(64) void k_conv(
    const unsigned short* __restrict__ z_pad, const unsigned short* __restrict__ Wfrag,
    const float* __restrict__ c_b, float* __restrict__ out) {
  static constexpr int DYt[28] = {0, -3,-3,-3,0,0,0,3,3,3,
                                     -5,-5,-5,0,0,0,5,5,5,
                                     -7,-7,-7,0,0,0,7,7,7};
  static constexpr int DXt[28] = {0, -3,0,3,-3,0,3,-3,0,3,
                                     -5,0,5,-5,0,5,-5,0,5,
                                     -7,0,7,-7,0,7,-7,0,7};
  int blk = blockIdx.x;                       // b(4) x h(64) x dt2(2) x wt2(2)
  int b = blk >> 8, h = (blk >> 2) & 63, dt2 = (blk >> 1) & 1, wt2 = blk & 1;
  int lane = threadIdx.x, quad = lane >> 4, l15 = lane & 15;
  const unsigned short* zb = z_pad + b*ZPB + ((h + 7)*78 + 7)*64 + quad*8;
  const bf16x8* wfp = (const bf16x8*)Wfrag + lane;
  int d0 = dt2*2 + 0, d1 = dt2*2 + 1;
  f32x4 cb0 = *(const f32x4*)(c_b + b*64 + d0*16 + quad*4);
  f32x4 cb1 = *(const f32x4*)(c_b + b*64 + d1*16 + quad*4);
  f32x4 acc00 = cb0, acc01 = cb0, acc10 = cb1, acc11 = cb1;
  int col0 = ((wt2*2 + 0)*16 + l15)*64;
  int col1 = ((wt2*2 + 1)*16 + l15)*64;
  #pragma unroll
  for (int tap = 0; tap < 28; ++tap) {
    int toff = (DYt[tap]*78 + DXt[tap])*64;
    const unsigned short* zrow = zb + toff;
    #pragma unroll
    for (int cc = 0; cc < 2; ++cc) {
      bf16x8 zf0 = *(const bf16x8*)(zrow + col0 + cc*32);
      bf16x8 zf1 = *(const bf16x8*)(zrow + col1 + cc*32);
      bf16x8 wf0 = wfp[((tap*4 + d0)*2 + cc)*64];
      bf16x8 wf1 = wfp[((tap*4 + d1)*2 + cc)*64];
      acc00 = MFMA(wf0, zf0, acc00);
      acc01 = MFMA(wf0, zf1, acc01);
      acc10 = MFMA(wf1, zf0, acc10);
      acc11 = MFMA(wf1, zf1, acc11);
    }
  }
  float* ob = out + b*262144 + h*64;
  int w0 = (wt2*2 + 0)*16 + l15, w1 = (wt2*2 + 1)*16 + l15;
  int dd0 = d0*16 + quad*4, dd1 = d1*16 + quad*4;
  ob[(dd0 + 0)*4096 + w0] = acc00.x;
  ob[(dd0 + 1)*4096 + w0] = acc00.y;
  ob[(dd0 + 2)*4096 + w0] = acc00.z;
  ob[(dd0 + 3)*4096 + w0] = acc00.w;
  ob[(dd0 + 0)*4096 + w1] = acc01.x;
  ob[(dd0 + 1)*4096 + w1] = acc01.y;
  ob[(dd0 + 2)*4096 + w1] = acc01.z;
  ob[(dd0 + 3)*4096 + w1] = acc01.w;
  ob[(dd1 + 0)*4096 + w0] = acc10.x;
  ob[(dd1 + 1)*4096 + w0] = acc10.y;
  ob[(dd1 + 2)*4096 + w0] = acc10.z;
  ob[(dd1 + 3)*4096 + w0] = acc10.w;
  ob[(dd1 + 0)*4096 + w1] = acc11.x;
  ob[(dd1 + 1)*4096 + w1] = acc11.y;
  ob[(dd1 + 2)*4096 + w1] = acc11.z;
  ob[(dd1 + 3)*4096 + w1] = acc11.w;
}

extern "C" void kernel_launch(void* const* d_in, const int* in_sizes, int n_in,
                              void* d_out, int out_size, void* d_ws, size_t ws_size,
                              hipStream_t stream) {
  const float* x    = (const float*)d_in[0];
  const float* g_w  = (const float*)d_in[1];
  const float* g_b  = (const float*)d_in[2];
  const float* th_w = (const float*)d_in[3];
  const float* th_b = (const float*)d_in[4];
  const float* ph_w = (const float*)d_in[5];
  const float* ph_b = (const float*)d_in[6];
  const float* Wz_w = (const float*)d_in[7];
  const float* Wz_b = (const float*)d_in[8];
  const float* bn_g = (const float*)d_in[9];
  const float* bn_b = (const float*)d_in[10];
  const float* am_w = (const float*)d_in[11];
  const float* am_b = (const float*)d_in[12];
  const float* a1_w = (const float*)d_in[13];
  const float* a1_b = (const float*)d_in[14];
  const float* a3_w = (const float*)d_in[15];
  const float* a3_b = (const float*)d_in[16];
  const float* a5_w = (const float*)d_in[17];
  const float* a5_b = (const float*)d_in[18];
  const float* a7_w = (const float*)d_in[19];
  const float* a7_b = (const float*)d_in[20];
  const float* out_w = (const float*)d_in[21];
  const float* out_b = (const float*)d_in[22];
  float* out = (float*)d_out;
  char* ws = (char*)d_ws;
  unsigned short* thetaB = (unsigned short*)(ws + 0);
  unsigned short* phiB   = (unsigned short*)(ws + 1048576);
  unsigned short* gB     = (unsigned short*)(ws + 2097152);
  unsigned short* z_pad  = (unsigned short*)(ws + 3145728);
  unsigned short* Wfrag  = (unsigned short*)(ws + 6260736);
  unsigned short* WzF    = (unsigned short*)(ws + 6490112);
  float* zmean           = (float*)(ws + 6494208);
  float* c_b             = (float*)(ws + 6495232);
  float* bias2           = (float*)(ws + 6496256);
  float* part            = (float*)(ws + 6496512);  // + 5,242,880 B

  k_zero<<<dim3(3042), dim3(256), 0, stream>>>((unsigned*)z_pad, zmean);
  k_prep<<<dim3(30), dim3(256), 0, stream>>>(out_w, a1_w, a3_w, a5_w, a7_w,
                                             Wz_w, bn_g, Wz_b, bn_b, Wfrag, WzF, bias2);
  k_qkv<<<dim3(192), dim3(256), 0, stream>>>(x, th_w, th_b, ph_w, ph_b, g_w, g_b,
                                             thetaB, phiB, gB);
  k_attn<<<dim3(1024), dim3(64), 0, stream>>>(thetaB, phiB, gB, part);
  k_merge<<<dim3(512), dim3(64), 0, stream>>>(part, WzF, bias2, x, z_pad);
  k_zmean<<<dim3(32), dim3(256), 0, stream>>>(z_pad, zmean);
  k_cb<<<dim3(4), dim3(64), 0, stream>>>(zmean, am_w, am_b, out_w, out_b,
                                         a1_b, a3_b, a5_b, a7_b, c_b);
  k_conv<<<dim3(1024), dim3(64), 0, stream>>>(z_pad, Wfrag, c_b, out);
}

// Round 3
// 187.279 us; speedup vs baseline: 2.0007x; 1.1442x over previous
//
#include <hip/hip_runtime.h>

// NonLocal (flash attention, d=32) + collapsed ASPP, all MFMA bf16 on gfx950.
// Layout conventions (A: m=lane&15,k=quad*8+j | B: n=lane&15,k=quad*8+j |
//                     D: n=lane&15,m=quad*4+r)

typedef __attribute__((ext_vector_type(8))) short bf16x8;
typedef __attribute__((ext_vector_type(4))) short s16x4;
typedef __attribute__((ext_vector_type(4))) float f32x4;

#define MFMA(a, b, c) __builtin_amdgcn_mfma_f32_16x16x32_bf16((a), (b), (c), 0, 0, 0)

#if __has_builtin(__builtin_amdgcn_exp2f)
#define EXP2(x) __builtin_amdgcn_exp2f(x)
#else
#define EXP2(x) exp2f(x)
#endif

__device__ static inline short f2bf(float f) {
  union { float f; unsigned u; } v; v.f = f;
  unsigned r = v.u + 0x7fffu + ((v.u >> 16) & 1u);
  return (short)(r >> 16);
}
__device__ static inline float bf2f(unsigned short h) {
  union { unsigned u; float f; } v; v.u = ((unsigned)h) << 16;
  return v.f;
}
__device__ static inline s16x4 pk4(f32x4 v) {
  s16x4 r; r.x = f2bf(v.x); r.y = f2bf(v.y); r.z = f2bf(v.z); r.w = f2bf(v.w);
  return r;
}
// truncating 2xfp32 -> packed bf16x2 dword (low16 = f0, high16 = f1)
__device__ static inline unsigned pk2(float f0, float f1) {
  union { float f; unsigned u; } a, b; a.f = f0; b.f = f1;
  return __builtin_amdgcn_perm(b.u, a.u, 0x07060302u);
}
__device__ static inline float unlo(unsigned d) {
  union { unsigned u; float f; } v; v.u = d << 16; return v.f;
}
__device__ static inline float unhi(unsigned d) {
  union { unsigned u; float f; } v; v.u = d & 0xffff0000u; return v.f;
}
__device__ static inline f32x4 exp24(f32x4 v) {
  f32x4 r; r.x = EXP2(v.x); r.y = EXP2(v.y); r.z = EXP2(v.z); r.w = EXP2(v.w);
  return r;
}

// ---------------- sizes ----------------
#define QF_PER_B 131072  // theta/phi/g frag elems per batch
#define ZPB      389376  // per-batch z_pad elems (78x78x64)
#define LOG2E    1.4426950408889634f

// ---------------- zero halo of z_pad + zmean ----------------
// Interior 64x64 is fully written by k_merge; only the width-7 halo ring
// (1988 px/batch) needs zeroing. 4 x 249 blocks + 1 for zmean.
__global__ __launch_bounds__(256) void k_zero(unsigned* zp, float* zmean) {
  int blk = blockIdx.x, t = threadIdx.x;
  if (blk == 996) { if (t < 256) zmean[t] = 0.f; return; }
  int b = blk / 249, loc = blk - b * 249;
  int i = loc * 256 + t;
  if (i >= 63616) return;
  int px = i >> 5, dw = i & 31;
  int row, col;
  if (px < 1092) {
    int r = px / 78; col = px - r * 78;
    row = (r < 7) ? r : r + 64;
  } else {
    int j = px - 1092;
    int r = j / 14; int c = j - r * 14;
    row = r + 7; col = (c < 7) ? c : c + 57;
  }
  zp[b * (ZPB / 2) + (row * 78 + col) * 32 + dw] = 0u;
}

// ---------------- weight prep: combined 28-tap kernels + folded Wz ----------------
__global__ __launch_bounds__(256) void k_prep(
    const float* __restrict__ out_w, const float* __restrict__ a1_w,
    const float* __restrict__ a3_w, const float* __restrict__ a5_w,
    const float* __restrict__ a7_w, const float* __restrict__ Wz_w,
    const float* __restrict__ bn_g, const float* __restrict__ Wz_b,
    const float* __restrict__ bn_b,
    unsigned short* __restrict__ Wfrag, unsigned short* __restrict__ WzF,
    float* __restrict__ bias2) {
  int blk = blockIdx.x, t = threadIdx.x;
  if (blk < 28) {
    __shared__ float wsm[4096];     // [m][c] for this tap's (ky,kx)
    __shared__ float osm[64 * 65];  // [d][m], stride 65
    int tap = blk;
    const float* w; int goff, kyx = 0, ksq = 9;
    if (tap == 0)      { w = a1_w; goff = 64;  ksq = 1; }
    else if (tap < 10) { w = a3_w; goff = 128; kyx = tap - 1; }
    else if (tap < 19) { w = a5_w; goff = 192; kyx = tap - 10; }
    else               { w = a7_w; goff = 256; kyx = tap - 19; }
    for (int i = t; i < 4096; i += 256) {
      wsm[i] = w[i * ksq + kyx];
      int d = i >> 6, m = i & 63;
      osm[d * 65 + m] = out_w[d * 320 + goff + m];
    }
    __syncthreads();
    int dt = t >> 6, lane = t & 63, quad = lane >> 4, l15 = lane & 15;
    int d = dt * 16 + l15;
    float acc[16];
    #pragma unroll
    for (int k = 0; k < 16; ++k) acc[k] = 0.f;
    const float* orow = osm + d * 65;
    int c0 = quad * 8;
    for (int m = 0; m < 64; ++m) {
      float o = orow[m];
      const float* wr = wsm + m * 64 + c0;
      #pragma unroll
      for (int cc = 0; cc < 2; ++cc)
        #pragma unroll
        for (int j = 0; j < 8; ++j)
          acc[cc * 8 + j] += o * wr[cc * 32 + j];
    }
    #pragma unroll
    for (int cc = 0; cc < 2; ++cc) {
      bf16x8 v;
      #pragma unroll
      for (int j = 0; j < 8; ++j) v[j] = f2bf(acc[cc * 8 + j]);
      *(bf16x8*)(Wfrag + (((tap * 4 + dt) * 2 + cc) * 64 + lane) * 8) = v;
    }
  } else if (blk == 28) {
    int ct = t >> 6, lane = t & 63, quad = lane >> 4, l15 = lane & 15;
    int c = ct * 16 + l15;
    float s = bn_g[c] * rsqrtf(1.f + 1e-5f);
    bf16x8 v;
    #pragma unroll
    for (int j = 0; j < 8; ++j) v[j] = f2bf(s * Wz_w[c * 32 + quad * 8 + j]);
    *(bf16x8*)(WzF + (ct * 64 + lane) * 8) = v;
  } else if (t < 64) {
    float s = bn_g[t] * rsqrtf(1.f + 1e-5f);
    bias2[t] = s * Wz_b[t] + bn_b[t];
  }
}

// ---------------- QKV 1x1 projections -> pre-swizzled bf16 fragments ----------------
// theta is pre-scaled by log2e so attention uses raw v_exp (exp2).
__global__ __launch_bounds__(256) void k_qkv(
    const float* __restrict__ x,
    const float* __restrict__ tw, const float* __restrict__ tb,
    const float* __restrict__ pw, const float* __restrict__ pb,
    const float* __restrict__ gw, const float* __restrict__ gb,
    unsigned short* __restrict__ thetaB, unsigned short* __restrict__ phiB,
    unsigned short* __restrict__ gB) {
  __shared__ float wl[2048];
  __shared__ float bl[32];
  int blk = blockIdx.x;
  int b = blk & 3, pt = (blk >> 2) & 15, proj = blk >> 6;
  const float* w    = proj == 0 ? tw : (proj == 1 ? pw : gw);
  const float* bias = proj == 0 ? tb : (proj == 1 ? pb : gb);
  int tid = threadIdx.x;
  for (int i = tid; i < 2048; i += 256) wl[i] = w[i];
  if (tid < 32) bl[tid] = bias[tid];
  __syncthreads();
  int pix = pt*256 + tid;
  const float* xp = x + b*64*4096 + pix;
  float acc[32];
  #pragma unroll
  for (int ci = 0; ci < 32; ++ci) acc[ci] = bl[ci];
  for (int c = 0; c < 64; ++c) {
    float xv = xp[c*4096];
    #pragma unroll
    for (int ci = 0; ci < 32; ++ci) acc[ci] += wl[ci*64 + c] * xv;
  }
  if (proj == 0) {
    #pragma unroll
    for (int ci = 0; ci < 32; ++ci) acc[ci] *= LOG2E;
  }
  if (proj < 2) {
    unsigned short* base = (proj == 0 ? thetaB : phiB) + b*QF_PER_B
                           + (pix >> 4)*512 + (pix & 15)*8;
    #pragma unroll
    for (int q = 0; q < 4; ++q) {
      bf16x8 v;
      #pragma unroll
      for (int j = 0; j < 8; ++j) v[j] = f2bf(acc[q*8 + j]);
      *(bf16x8*)(base + q*128) = v;
    }
  } else {
    unsigned short* base = gB + b*QF_PER_B + (pix >> 5)*1024
                           + ((pix & 31) >> 3)*128 + (pix & 7);
    #pragma unroll
    for (int ci = 0; ci < 32; ++ci)
      base[(ci >> 4)*512 + (ci & 15)*8] = (unsigned short)f2bf(acc[ci]);
  }
}

// ---------------- flash attention (no-max softmax, K-split=4) ----------------
// 2048 single-wave blocks -> 2 waves/SIMD. Transpose rows stride 36 shorts
// (18 dwords: gcd(18,32)=2 -> 16 distinct banks, uniform access, 0 conflicts).
// l accumulated via MFMA with ones-A. Partials stored packed bf16.
__global__ __launch_bounds__(64) void k_attn(
    const unsigned short* __restrict__ thetaB, const unsigned short* __restrict__ phiB,
    const unsigned short* __restrict__ gB, unsigned* __restrict__ part) {
  __shared__ __align__(16) unsigned short plds[1152];  // 2 qt x 16 rows x 36
  int blk = blockIdx.x;                       // b(4) x qblk(128) x kh(4)
  int b = blk >> 9, qblk = (blk >> 2) & 127, kh = blk & 3;
  int lane = threadIdx.x, quad = lane >> 4, l15 = lane & 15;
  const bf16x8* thB = (const bf16x8*)(thetaB + b*QF_PER_B);
  const bf16x8* phF = (const bf16x8*)(phiB + b*QF_PER_B);
  const bf16x8* gF  = (const bf16x8*)(gB + b*QF_PER_B);
  bf16x8 th0 = thB[(qblk*2 + 0)*64 + lane];
  bf16x8 th1 = thB[(qblk*2 + 1)*64 + lane];
  bf16x8 ones;
  #pragma unroll
  for (int j = 0; j < 8; ++j) ones[j] = (short)0x3F80;
  const f32x4 z4 = {0.f, 0.f, 0.f, 0.f};
  f32x4 acc00 = z4, acc01 = z4, acc10 = z4, acc11 = z4;  // [qt][tc] of Y^T
  f32x4 accL0 = z4, accL1 = z4;                          // softmax denominators
  unsigned short* r0p = plds + l15*36 + quad*4;          // write rows
  unsigned short* r1p = plds + 576 + l15*36 + quad*4;
  const unsigned short* q0p = plds + l15*36 + quad*8;    // read rows
  const unsigned short* q1p = plds + 576 + l15*36 + quad*8;
  int kt0 = kh*32;
  for (int kt = kt0; kt < kt0 + 32; ++kt) {
    int tbase = kt*128 + lane;
    bf16x8 pf0 = phF[tbase];
    bf16x8 pf1 = phF[tbase + 64];
    bf16x8 gf0 = gF[tbase];
    bf16x8 gf1 = gF[tbase + 64];
    f32x4 s00 = MFMA(pf0, th0, z4);   // S^T[k0..15][q of qt0]
    f32x4 s10 = MFMA(pf1, th0, z4);   // S^T[k16..31]
    f32x4 s01 = MFMA(pf0, th1, z4);
    f32x4 s11 = MFMA(pf1, th1, z4);
    f32x4 p00 = exp24(s00), p10 = exp24(s10), p01 = exp24(s01), p11 = exp24(s11);
    // truncating pack + transpose via LDS (lane holds k=quad*4+r, q=l15)
    uint2 w0; w0.x = pk2(p00.x, p00.y); w0.y = pk2(p00.z, p00.w);
    uint2 w1; w1.x = pk2(p10.x, p10.y); w1.y = pk2(p10.z, p10.w);
    uint2 w2; w2.x = pk2(p01.x, p01.y); w2.y = pk2(p01.z, p01.w);
    uint2 w3; w3.x = pk2(p11.x, p11.y); w3.y = pk2(p11.z, p11.w);
    *(uint2*)(r0p)      = w0;
    *(uint2*)(r0p + 16) = w1;
    *(uint2*)(r1p)      = w2;
    *(uint2*)(r1p + 16) = w3;
    uint2 a0 = *(const uint2*)(q0p);
    uint2 a1 = *(const uint2*)(q0p + 4);
    uint2 b0 = *(const uint2*)(q1p);
    uint2 b1 = *(const uint2*)(q1p + 4);
    union { unsigned u[4]; bf16x8 v; } pb0c, pb1c;
    pb0c.u[0] = a0.x; pb0c.u[1] = a0.y; pb0c.u[2] = a1.x; pb0c.u[3] = a1.y;
    pb1c.u[0] = b0.x; pb1c.u[1] = b0.y; pb1c.u[2] = b1.x; pb1c.u[3] = b1.y;
    acc00 = MFMA(gf0, pb0c.v, acc00);   // Y^T[ci 0..15][q qt0]
    acc01 = MFMA(gf1, pb0c.v, acc01);   // ci 16..31
    acc10 = MFMA(gf0, pb1c.v, acc10);
    acc11 = MFMA(gf1, pb1c.v, acc11);
    accL0 = MFMA(ones, pb0c.v, accL0);  // every lane: l(q=l15)
    accL1 = MFMA(ones, pb1c.v, accL1);
  }
  unsigned* pp = part + blk*640;
  uint4 y0, y1;
  y0.x = pk2(acc00.x, acc00.y); y0.y = pk2(acc00.z, acc00.w);
  y0.z = pk2(acc01.x, acc01.y); y0.w = pk2(acc01.z, acc01.w);
  y1.x = pk2(acc10.x, acc10.y); y1.y = pk2(acc10.z, acc10.w);
  y1.z = pk2(acc11.x, acc11.y); y1.w = pk2(acc11.z, acc11.w);
  *(uint4*)(pp + lane*8)     = y0;
  *(uint4*)(pp + lane*8 + 4) = y1;
  float* lp = (float*)(pp + 512);
  lp[lane*2]     = accL0.x;
  lp[lane*2 + 1] = accL1.x;
}

// ---------------- merge 4 K-partials + Wz(+BN) + residual -> z_pad bf16 ----------------
__global__ __launch_bounds__(64) void k_merge(
    const unsigned* __restrict__ part, const unsigned short* __restrict__ WzF,
    const float* __restrict__ bias2, const float* __restrict__ x,
    unsigned short* __restrict__ z_pad) {
  __shared__ __align__(16) unsigned short ylds[1280];
  int blk = blockIdx.x;                       // b(4) x qblk(128)
  int b = blk >> 7, qblk = blk & 127;
  int lane = threadIdx.x, quad = lane >> 4, l15 = lane & 15;
  const f32x4 z4 = {0.f, 0.f, 0.f, 0.f};
  f32x4 a00 = z4, a01 = z4, a10 = z4, a11 = z4;
  float l0 = 0.f, l1 = 0.f;
  #pragma unroll
  for (int kh = 0; kh < 4; ++kh) {
    const unsigned* pp = part + (blk*4 + kh)*640;
    uint4 A = *(const uint4*)(pp + lane*8);
    uint4 B = *(const uint4*)(pp + lane*8 + 4);
    a00.x += unlo(A.x); a00.y += unhi(A.x); a00.z += unlo(A.y); a00.w += unhi(A.y);
    a01.x += unlo(A.z); a01.y += unhi(A.z); a01.z += unlo(A.w); a01.w += unhi(A.w);
    a10.x += unlo(B.x); a10.y += unhi(B.x); a10.z += unlo(B.y); a10.w += unhi(B.y);
    a11.x += unlo(B.z); a11.y += unhi(B.z); a11.z += unlo(B.w); a11.w += unhi(B.w);
    const float* lp = (const float*)(pp + 512);
    l0 += lp[lane*2]; l1 += lp[lane*2 + 1];
  }
  float r0 = 1.f / l0, r1 = 1.f / l1;
  a00 *= r0; a01 *= r0; a10 *= r1; a11 *= r1;
  // lane holds (ci=tc*16+quad*4+r, q=qt*16+l15) -> yB[q][ci], stride 40
  *(s16x4*)(ylds + l15*40 + quad*4)             = pk4(a00);
  *(s16x4*)(ylds + l15*40 + 16 + quad*4)        = pk4(a01);
  *(s16x4*)(ylds + (16 + l15)*40 + quad*4)      = pk4(a10);
  *(s16x4*)(ylds + (16 + l15)*40 + 16 + quad*4) = pk4(a11);
  bf16x8 y0 = *(const bf16x8*)(ylds + l15*40 + quad*8);
  bf16x8 y1 = *(const bf16x8*)(ylds + (16 + l15)*40 + quad*8);
  const bf16x8* wzf = (const bf16x8*)WzF;
  int q0 = qblk * 32;
  #pragma unroll
  for (int ct = 0; ct < 4; ++ct) {
    bf16x8 wf = wzf[ct*64 + lane];
    f32x4 zq0 = MFMA(wf, y0, z4);
    f32x4 zq1 = MFMA(wf, y1, z4);
    int c0 = ct*16 + quad*4;
    f32x4 b2 = *(const f32x4*)(bias2 + c0);
    #pragma unroll
    for (int qt = 0; qt < 2; ++qt) {
      f32x4 zz = qt ? zq1 : zq0;
      int q = q0 + qt*16 + l15;
      int h = q >> 6, w = q & 63;
      const float* xp = x + (b*64 + c0)*4096 + q;
      s16x4 pkv;
      pkv.x = f2bf(zz.x + b2.x + xp[0]);
      pkv.y = f2bf(zz.y + b2.y + xp[4096]);
      pkv.z = f2bf(zz.z + b2.z + xp[8192]);
      pkv.w = f2bf(zz.w + b2.w + xp[12288]);
      *(s16x4*)(z_pad + b*ZPB + ((h + 7)*78 + (w + 7))*64 + c0) = pkv;
    }
  }
}

// ---------------- channel mean of z (partial + atomic) ----------------
__global__ __launch_bounds__(256) void k_zmean(const unsigned short* __restrict__ z_pad,
                                               float* __restrict__ zmean) {
  __shared__ float red[256];
  int blk = blockIdx.x;                       // b(4) x chunk(64)
  int b = blk >> 6, ch = blk & 63;
  int t = threadIdx.x, c = t & 63, pg = t >> 6;
  const unsigned short* zp = z_pad + b*ZPB;
  float s = 0.f;
  for (int k = 0; k < 16; ++k) {
    int pix = ch*64 + pg*16 + k;
    int row = (pix >> 6) + 7, col = (pix & 63) + 7;
    s += bf2f(zp[(row*78 + col)*64 + c]);
  }
  red[t] = s;
  __syncthreads();
  if (t < 64)
    atomicAdd(zmean + b*64 + c, red[t] + red[64 + t] + red[128 + t] + red[192 + t]);
}

// ---------------- per-(b,d) constant: img branch + all biases ----------------
__global__ __launch_bounds__(64) void k_cb(
    const float* __restrict__ zmean, const float* __restrict__ am_w,
    const float* __restrict__ am_b, const float* __restrict__ out_w,
    const float* __restrict__ out_b, const float* __restrict__ a1_b,
    const float* __restrict__ a3_b, const float* __restrict__ a5_b,
    const float* __restrict__ a7_b, float* __restrict__ c_b) {
  __shared__ float img[64];
  int b = blockIdx.x, d = threadIdx.x;
  float s = am_b[d];
  for (int c = 0; c < 64; ++c)
    s += am_w[d*64 + c] * (zmean[b*64 + c] * (1.f / 4096.f));
  img[d] = s;
  __syncthreads();
  const float* ow = out_w + d*320;
  float r = out_b[d];
  for (int dd = 0; dd < 64; ++dd) r += ow[dd] * img[dd];
  for (int m = 0; m < 64; ++m)
    r += ow[64 + m]*a1_b[m] + ow[128 + m]*a3_b[m] + ow[192 + m]*a5_b[m] + ow[256 + m]*a7_b[m];
  c_b[b*64 + d] = r;
}

// ---------------- collapsed 28-tap ASPP conv (implicit GEMM) ----------------
__global__ __launch_bounds__(64) void k_conv(
    const unsigned short* __restrict__ z_pad, const unsigned short* __restrict__ Wfrag,
    const float* __restrict__ c_b, float* __restrict__ out) {
  static constexpr int DYt[28] = {0, -3,-3,-3,0,0,0,3,3,3,
                                     -5,-5,-5,0,0,0,5,5,5,
                                     -7,-7,-7,0,0,0,7,7,7};
  static constexpr int DXt[28] = {0, -3,0,3,-3,0,3,-3,0,3,
                                     -5,0,5,-5,0,5,-5,0,5,
                                     -7,0,7,-7,0,7,-7,0,7};
  int blk = blockIdx.x;                       // b(4) x h(64) x dt2(2) x wt2(2)
  int b = blk >> 8, h = (blk >> 2) & 63, dt2 = (blk >> 1) & 1, wt2 = blk & 1;
  int lane = threadIdx.x, quad = lane >> 4, l15 = lane & 15;
  const unsigned short* zb = z_pad + b*ZPB + ((h + 7)*78 + 7)*64 + quad*8;
  const bf16x8* wfp = (const bf16x8*)Wfrag + lane;
  int d0 = dt2*2 + 0, d1 = dt2*2 + 1;
  f32x4 cb0 = *(const f32x4*)(c_b + b*64 + d0*16 + quad*4);
  f32x4 cb1 = *(const f32x4*)(c_b + b*64 + d1*16 + quad*4);
  f32x4 acc00 = cb0, acc01 = cb0, acc10 = cb1, acc11 = cb1;
  int col0 = ((wt2*2 + 0)*16 + l15)*64;
  int col1 = ((wt2*2 + 1)*16 + l15)*64;
  #pragma unroll
  for (int tap = 0; tap < 28; ++tap) {
    int toff = (DYt[tap]*78 + DXt[tap])*64;
    const unsigned short* zrow = zb + toff;
    #pragma unroll
    for (int cc = 0; cc < 2; ++cc) {
      bf16x8 zf0 = *(const bf16x8*)(zrow + col0 + cc*32);
      bf16x8 zf1 = *(const bf16x8*)(zrow + col1 + cc*32);
      bf16x8 wf0 = wfp[((tap*4 + d0)*2 + cc)*64];
      bf16x8 wf1 = wfp[((tap*4 + d1)*2 + cc)*64];
      acc00 = MFMA(wf0, zf0, acc00);
      acc01 = MFMA(wf0, zf1, acc01);
      acc10 = MFMA(wf1, zf0, acc10);
      acc11 = MFMA(wf1, zf1, acc11);
    }
  }
  float* ob = out + b*262144 + h*64;
  int w0 = (wt2*2 + 0)*16 + l15, w1 = (wt2*2 + 1)*16 + l15;
  int dd0 = d0*16 + quad*4, dd1 = d1*16 + quad*4;
  ob[(dd0 + 0)*4096 + w0] = acc00.x;
  ob[(dd0 + 1)*4096 + w0] = acc00.y;
  ob[(dd0 + 2)*4096 + w0] = acc00.z;
  ob[(dd0 + 3)*4096 + w0] = acc00.w;
  ob[(dd0 + 0)*4096 + w1] = acc01.x;
  ob[(dd0 + 1)*4096 + w1] = acc01.y;
  ob[(dd0 + 2)*4096 + w1] = acc01.z;
  ob[(dd0 + 3)*4096 + w1] = acc01.w;
  ob[(dd1 + 0)*4096 + w0] = acc10.x;
  ob[(dd1 + 1)*4096 + w0] = acc10.y;
  ob[(dd1 + 2)*4096 + w0] = acc10.z;
  ob[(dd1 + 3)*4096 + w0] = acc10.w;
  ob[(dd1 + 0)*4096 + w1] = acc11.x;
  ob[(dd1 + 1)*4096 + w1] = acc11.y;
  ob[(dd1 + 2)*4096 + w1] = acc11.z;
  ob[(dd1 + 3)*4096 + w1] = acc11.w;
}

extern "C" void kernel_launch(void* const* d_in, const int* in_sizes, int n_in,
                              void* d_out, int out_size, void* d_ws, size_t ws_size,
                              hipStream_t stream) {
  const float* x    = (const float*)d_in[0];
  const float* g_w  = (const float*)d_in[1];
  const float* g_b  = (const float*)d_in[2];
  const float* th_w = (const float*)d_in[3];
  const float* th_b = (const float*)d_in[4];
  const float* ph_w = (const float*)d_in[5];
  const float* ph_b = (const float*)d_in[6];
  const float* Wz_w = (const float*)d_in[7];
  const float* Wz_b = (const float*)d_in[8];
  const float* bn_g = (const float*)d_in[9];
  const float* bn_b = (const float*)d_in[10];
  const float* am_w = (const float*)d_in[11];
  const float* am_b = (const float*)d_in[12];
  const float* a1_w = (const float*)d_in[13];
  const float* a1_b = (const float*)d_in[14];
  const float* a3_w = (const float*)d_in[15];
  const float* a3_b = (const float*)d_in[16];
  const float* a5_w = (const float*)d_in[17];
  const float* a5_b = (const float*)d_in[18];
  const float* a7_w = (const float*)d_in[19];
  const float* a7_b = (const float*)d_in[20];
  const float* out_w = (const float*)d_in[21];
  const float* out_b = (const float*)d_in[22];
  float* out = (float*)d_out;
  char* ws = (char*)d_ws;
  unsigned short* thetaB = (unsigned short*)(ws + 0);
  unsigned short* phiB   = (unsigned short*)(ws + 1048576);
  unsigned short* gB     = (unsigned short*)(ws + 2097152);
  unsigned short* z_pad  = (unsigned short*)(ws + 3145728);
  unsigned short* Wfrag  = (unsigned short*)(ws + 6260736);
  unsigned short* WzF    = (unsigned short*)(ws + 6490112);
  float* zmean           = (float*)(ws + 6494208);
  float* c_b             = (float*)(ws + 6495232);
  float* bias2           = (float*)(ws + 6496256);
  unsigned* part         = (unsigned*)(ws + 6496512);  // 2048*640*4 = 5,242,880 B

  k_zero<<<dim3(997), dim3(256), 0, stream>>>((unsigned*)z_pad, zmean);
  k_prep<<<dim3(30), dim3(256), 0, stream>>>(out_w, a1_w, a3_w, a5_w, a7_w,
                                             Wz_w, bn_g, Wz_b, bn_b, Wfrag, WzF, bias2);
  k_qkv<<<dim3(192), dim3(256), 0, stream>>>(x, th_w, th_b, ph_w, ph_b, g_w, g_b,
                                             thetaB, phiB, gB);
  k_attn<<<dim3(2048), dim3(64), 0, stream>>>(thetaB, phiB, gB, part);
  k_merge<<<dim3(512), dim3(64), 0, stream>>>(part, WzF, bias2, x, z_pad);
  k_zmean<<<dim3(256), dim3(256), 0, stream>>>(z_pad, zmean);
  k_cb<<<dim3(4), dim3(64), 0, stream>>>(zmean, am_w, am_b, out_w, out_b,
                                         a1_b, a3_b, a5_b, a7_b, c_b);
  k_conv<<<dim3(1024), dim3(64), 0, stream>>>(z_pad, Wfrag, c_b, out);
}

// Round 4
// 182.220 us; speedup vs baseline: 2.0562x; 1.0278x over previous
//
#include <hip/hip_runtime.h>

// NonLocal (flash attention, d=32) + collapsed ASPP, all MFMA bf16 on gfx950.
// 3 dispatches: setup (zero+prep+qkv+transposes), attn (QK^T/softmax/PV +
// in-LDS K-merge + Wz+BN+residual + zmean atomics), conv (28-tap implicit
// GEMM with inlined c_b).
// Layout conventions (A: m=lane&15,k=quad*8+j | B: n=lane&15,k=quad*8+j |
//                     D: n=lane&15,m=quad*4+r)

typedef __attribute__((ext_vector_type(8))) short bf16x8;
typedef __attribute__((ext_vector_type(4))) short s16x4;
typedef __attribute__((ext_vector_type(4))) float f32x4;

#define MFMA(a, b, c) __builtin_amdgcn_mfma_f32_16x16x32_bf16((a), (b), (c), 0, 0, 0)

#if __has_builtin(__builtin_amdgcn_exp2f)
#define EXP2(x) __builtin_amdgcn_exp2f(x)
#else
#define EXP2(x) exp2f(x)
#endif

__device__ static inline short f2bf(float f) {
  union { float f; unsigned u; } v; v.f = f;
  unsigned r = v.u + 0x7fffu + ((v.u >> 16) & 1u);
  return (short)(r >> 16);
}
__device__ static inline float bf2f(unsigned short h) {
  union { unsigned u; float f; } v; v.u = ((unsigned)h) << 16;
  return v.f;
}
__device__ static inline s16x4 pk4(f32x4 v) {
  s16x4 r; r.x = f2bf(v.x); r.y = f2bf(v.y); r.z = f2bf(v.z); r.w = f2bf(v.w);
  return r;
}
// truncating 2xfp32 -> packed bf16x2 dword (low16 = f0, high16 = f1)
__device__ static inline unsigned pk2(float f0, float f1) {
  union { float f; unsigned u; } a, b; a.f = f0; b.f = f1;
  return __builtin_amdgcn_perm(b.u, a.u, 0x07060302u);
}
__device__ static inline f32x4 exp24(f32x4 v) {
  f32x4 r; r.x = EXP2(v.x); r.y = EXP2(v.y); r.z = EXP2(v.z); r.w = EXP2(v.w);
  return r;
}

// ---------------- sizes ----------------
#define QF_PER_B 131072  // theta/phi/g frag elems per batch
#define ZPB      389376  // per-batch z_pad elems (78x78x64)
#define LOG2E    1.4426950408889634f

// ================= k_setup: zero + prep + qkv + transposes =================
// blocks [0,997): z_pad halo + zmean zero
// blocks [997,1027): 28-tap combined weights + WzF + bias2
// blocks [1027,1219): QKV projections
// block 1219: am_wT / owT0 / cbias
__global__ __launch_bounds__(256) void k_setup(
    const float* __restrict__ x,
    const float* __restrict__ tw, const float* __restrict__ tb,
    const float* __restrict__ pw, const float* __restrict__ pb,
    const float* __restrict__ gw, const float* __restrict__ gb,
    const float* __restrict__ out_w, const float* __restrict__ out_b,
    const float* __restrict__ a1_w, const float* __restrict__ a3_w,
    const float* __restrict__ a5_w, const float* __restrict__ a7_w,
    const float* __restrict__ a1_b, const float* __restrict__ a3_b,
    const float* __restrict__ a5_b, const float* __restrict__ a7_b,
    const float* __restrict__ Wz_w, const float* __restrict__ Wz_b,
    const float* __restrict__ bn_g, const float* __restrict__ bn_b,
    const float* __restrict__ am_w,
    unsigned* __restrict__ zp, float* __restrict__ zmean,
    unsigned short* __restrict__ Wfrag, unsigned short* __restrict__ WzF,
    float* __restrict__ bias2,
    unsigned short* __restrict__ thetaB, unsigned short* __restrict__ phiB,
    unsigned short* __restrict__ gB,
    float* __restrict__ am_wT, float* __restrict__ owT0,
    float* __restrict__ cbias) {
  __shared__ union {
    struct { float wsm[4096]; float osm[64 * 65]; } prep;
    struct { float wl[2048]; float bl[32]; } qkv;
  } sm;
  int blk = blockIdx.x, t = threadIdx.x;
  if (blk < 997) {
    // ---- zero halo ring of z_pad (+ zmean) ----
    if (blk == 996) { if (t < 256) zmean[t] = 0.f; return; }
    int b = blk / 249, loc = blk - b * 249;
    int i = loc * 256 + t;
    if (i >= 63616) return;
    int px = i >> 5, dw = i & 31;
    int row, col;
    if (px < 1092) {
      int r = px / 78; col = px - r * 78;
      row = (r < 7) ? r : r + 64;
    } else {
      int j = px - 1092;
      int r = j / 14; int c = j - r * 14;
      row = r + 7; col = (c < 7) ? c : c + 57;
    }
    zp[b * (ZPB / 2) + (row * 78 + col) * 32 + dw] = 0u;
  } else if (blk < 1027) {
    // ---- weight prep ----
    int pblk = blk - 997;
    if (pblk < 28) {
      int tap = pblk;
      const float* w; int goff, kyx = 0, ksq = 9;
      if (tap == 0)      { w = a1_w; goff = 64;  ksq = 1; }
      else if (tap < 10) { w = a3_w; goff = 128; kyx = tap - 1; }
      else if (tap < 19) { w = a5_w; goff = 192; kyx = tap - 10; }
      else               { w = a7_w; goff = 256; kyx = tap - 19; }
      for (int i = t; i < 4096; i += 256) {
        sm.prep.wsm[i] = w[i * ksq + kyx];
        int d = i >> 6, m = i & 63;
        sm.prep.osm[d * 65 + m] = out_w[d * 320 + goff + m];
      }
      __syncthreads();
      int dt = t >> 6, lane = t & 63, quad = lane >> 4, l15 = lane & 15;
      int d = dt * 16 + l15;
      float acc[16];
      #pragma unroll
      for (int k = 0; k < 16; ++k) acc[k] = 0.f;
      const float* orow = sm.prep.osm + d * 65;
      int c0 = quad * 8;
      for (int m = 0; m < 64; ++m) {
        float o = orow[m];
        const float* wr = sm.prep.wsm + m * 64 + c0;
        #pragma unroll
        for (int cc = 0; cc < 2; ++cc)
          #pragma unroll
          for (int j = 0; j < 8; ++j)
            acc[cc * 8 + j] += o * wr[cc * 32 + j];
      }
      #pragma unroll
      for (int cc = 0; cc < 2; ++cc) {
        bf16x8 v;
        #pragma unroll
        for (int j = 0; j < 8; ++j) v[j] = f2bf(acc[cc * 8 + j]);
        *(bf16x8*)(Wfrag + (((tap * 4 + dt) * 2 + cc) * 64 + lane) * 8) = v;
      }
    } else if (pblk == 28) {
      int ct = t >> 6, lane = t & 63, quad = lane >> 4, l15 = lane & 15;
      int c = ct * 16 + l15;
      float s = bn_g[c] * rsqrtf(1.f + 1e-5f);
      bf16x8 v;
      #pragma unroll
      for (int j = 0; j < 8; ++j) v[j] = f2bf(s * Wz_w[c * 32 + quad * 8 + j]);
      *(bf16x8*)(WzF + (ct * 64 + lane) * 8) = v;
    } else if (t < 64) {
      float s = bn_g[t] * rsqrtf(1.f + 1e-5f);
      bias2[t] = s * Wz_b[t] + bn_b[t];
    }
  } else if (blk < 1219) {
    // ---- QKV projections (theta prescaled by log2e) ----
    int qb = blk - 1027;
    int b = qb & 3, pt = (qb >> 2) & 15, proj = qb >> 6;
    const float* w    = proj == 0 ? tw : (proj == 1 ? pw : gw);
    const float* bias = proj == 0 ? tb : (proj == 1 ? pb : gb);
    for (int i = t; i < 2048; i += 256) sm.qkv.wl[i] = w[i];
    if (t < 32) sm.qkv.bl[t] = bias[t];
    __syncthreads();
    int pix = pt*256 + t;
    const float* xp = x + b*64*4096 + pix;
    float acc[32];
    #pragma unroll
    for (int ci = 0; ci < 32; ++ci) acc[ci] = sm.qkv.bl[ci];
    for (int c = 0; c < 64; ++c) {
      float xv = xp[c*4096];
      #pragma unroll
      for (int ci = 0; ci < 32; ++ci) acc[ci] += sm.qkv.wl[ci*64 + c] * xv;
    }
    if (proj == 0) {
      #pragma unroll
      for (int ci = 0; ci < 32; ++ci) acc[ci] *= LOG2E;
    }
    if (proj < 2) {
      unsigned short* base = (proj == 0 ? thetaB : phiB) + b*QF_PER_B
                             + (pix >> 4)*512 + (pix & 15)*8;
      #pragma unroll
      for (int q = 0; q < 4; ++q) {
        bf16x8 v;
        #pragma unroll
        for (int j = 0; j < 8; ++j) v[j] = f2bf(acc[q*8 + j]);
        *(bf16x8*)(base + q*128) = v;
      }
    } else {
      unsigned short* base = gB + b*QF_PER_B + (pix >> 5)*1024
                             + ((pix & 31) >> 3)*128 + (pix & 7);
      #pragma unroll
      for (int ci = 0; ci < 32; ++ci)
        base[(ci >> 4)*512 + (ci & 15)*8] = (unsigned short)f2bf(acc[ci]);
    }
  } else {
    // ---- transposed aux weights for conv's inlined c_b ----
    for (int i = t; i < 4096; i += 256) {
      int d = i >> 6, c = i & 63;
      am_wT[c * 64 + d] = am_w[i];               // am_w[d][c] -> [c][d]
      owT0[c * 64 + d] = out_w[d * 320 + c];     // ow[d][dd]  -> [dd][d]
    }
    if (t < 64) {
      float r = out_b[t];
      const float* ow = out_w + t * 320;
      for (int m = 0; m < 64; ++m)
        r += ow[64 + m] * a1_b[m] + ow[128 + m] * a3_b[m]
           + ow[192 + m] * a5_b[m] + ow[256 + m] * a7_b[m];
      cbias[t] = r;
    }
  }
}

// ====== k_attn: flash attention, K-split=8 in-block, fused merge/Wz/zmean ======
// block = (b, qblk): 8 waves, wave kh handles keys [kh*512, kh*512+512).
// Partials in LDS (f32). Waves 0..3 then merge + softmax-div + Wz(+BN) +
// residual + z_pad store + zmean shfl-reduce/atomics.
__global__ __launch_bounds__(512) void k_attn(
    const unsigned short* __restrict__ thetaB, const unsigned short* __restrict__ phiB,
    const unsigned short* __restrict__ gB, const unsigned short* __restrict__ WzF,
    const float* __restrict__ bias2, const float* __restrict__ x,
    unsigned short* __restrict__ z_pad, float* __restrict__ zmean) {
  __shared__ float ypart[8][64][20];                    // 16 y + l0,l1 (+2 pad)
  __shared__ __align__(16) unsigned short plds[8][1152];
  __shared__ __align__(16) unsigned short ytr[4][1280];
  int blk = blockIdx.x;                       // b(4) x qblk(128)
  int b = blk >> 7, qblk = blk & 127;
  int tid = threadIdx.x;
  int kh = tid >> 6, lane = tid & 63, quad = lane >> 4, l15 = lane & 15;
  const bf16x8* thB = (const bf16x8*)(thetaB + b*QF_PER_B);
  const bf16x8* phF = (const bf16x8*)(phiB + b*QF_PER_B);
  const bf16x8* gF  = (const bf16x8*)(gB + b*QF_PER_B);
  bf16x8 th0 = thB[(qblk*2 + 0)*64 + lane];
  bf16x8 th1 = thB[(qblk*2 + 1)*64 + lane];
  bf16x8 ones;
  #pragma unroll
  for (int j = 0; j < 8; ++j) ones[j] = (short)0x3F80;
  const f32x4 z4 = {0.f, 0.f, 0.f, 0.f};
  f32x4 acc00 = z4, acc01 = z4, acc10 = z4, acc11 = z4;  // [qt][tc] of Y^T
  f32x4 accL0 = z4, accL1 = z4;                          // softmax denominators
  unsigned short* pl = &plds[kh][0];
  unsigned short* r0p = pl + l15*36 + quad*4;
  unsigned short* r1p = pl + 576 + l15*36 + quad*4;
  const unsigned short* q0p = pl + l15*36 + quad*8;
  const unsigned short* q1p = pl + 576 + l15*36 + quad*8;
  int kt0 = kh*16;
  for (int kt = kt0; kt < kt0 + 16; ++kt) {
    int tbase = kt*128 + lane;
    bf16x8 pf0 = phF[tbase];
    bf16x8 pf1 = phF[tbase + 64];
    bf16x8 gf0 = gF[tbase];
    bf16x8 gf1 = gF[tbase + 64];
    f32x4 s00 = MFMA(pf0, th0, z4);   // S^T[k0..15][q of qt0]
    f32x4 s10 = MFMA(pf1, th0, z4);   // S^T[k16..31]
    f32x4 s01 = MFMA(pf0, th1, z4);
    f32x4 s11 = MFMA(pf1, th1, z4);
    f32x4 p00 = exp24(s00), p10 = exp24(s10), p01 = exp24(s01), p11 = exp24(s11);
    uint2 w0; w0.x = pk2(p00.x, p00.y); w0.y = pk2(p00.z, p00.w);
    uint2 w1; w1.x = pk2(p10.x, p10.y); w1.y = pk2(p10.z, p10.w);
    uint2 w2; w2.x = pk2(p01.x, p01.y); w2.y = pk2(p01.z, p01.w);
    uint2 w3; w3.x = pk2(p11.x, p11.y); w3.y = pk2(p11.z, p11.w);
    *(uint2*)(r0p)      = w0;
    *(uint2*)(r0p + 16) = w1;
    *(uint2*)(r1p)      = w2;
    *(uint2*)(r1p + 16) = w3;
    uint2 a0 = *(const uint2*)(q0p);
    uint2 a1 = *(const uint2*)(q0p + 4);
    uint2 b0 = *(const uint2*)(q1p);
    uint2 b1 = *(const uint2*)(q1p + 4);
    union { unsigned u[4]; bf16x8 v; } pb0c, pb1c;
    pb0c.u[0] = a0.x; pb0c.u[1] = a0.y; pb0c.u[2] = a1.x; pb0c.u[3] = a1.y;
    pb1c.u[0] = b0.x; pb1c.u[1] = b0.y; pb1c.u[2] = b1.x; pb1c.u[3] = b1.y;
    acc00 = MFMA(gf0, pb0c.v, acc00);   // Y^T[ci 0..15][q qt0]
    acc01 = MFMA(gf1, pb0c.v, acc01);   // ci 16..31
    acc10 = MFMA(gf0, pb1c.v, acc10);
    acc11 = MFMA(gf1, pb1c.v, acc11);
    accL0 = MFMA(ones, pb0c.v, accL0);  // l(q=l15) in every lane
    accL1 = MFMA(ones, pb1c.v, accL1);
  }
  float* yp = &ypart[kh][lane][0];
  *(f32x4*)(yp + 0)  = acc00;
  *(f32x4*)(yp + 4)  = acc01;
  *(f32x4*)(yp + 8)  = acc10;
  *(f32x4*)(yp + 12) = acc11;
  yp[16] = accL0.x; yp[17] = accL1.x;
  __syncthreads();
  if (kh >= 4) return;
  // ---- merge phase: wave ct handles c_out tile ct ----
  int ct = kh;
  f32x4 a00 = z4, a01 = z4, a10 = z4, a11 = z4;
  float l0 = 0.f, l1 = 0.f;
  #pragma unroll
  for (int k = 0; k < 8; ++k) {
    const float* q = &ypart[k][lane][0];
    a00 += *(const f32x4*)(q + 0);
    a01 += *(const f32x4*)(q + 4);
    a10 += *(const f32x4*)(q + 8);
    a11 += *(const f32x4*)(q + 12);
    l0 += q[16]; l1 += q[17];
  }
  float r0 = 1.f / l0, r1 = 1.f / l1;
  a00 *= r0; a01 *= r0; a10 *= r1; a11 *= r1;
  // transpose D-layout (q=l15, ci=quad*4+r) -> B-layout (q=l15, ci=quad*8+j)
  unsigned short* yl = &ytr[ct][0];
  *(s16x4*)(yl + l15*40 + quad*4)             = pk4(a00);
  *(s16x4*)(yl + l15*40 + 16 + quad*4)        = pk4(a01);
  *(s16x4*)(yl + (16 + l15)*40 + quad*4)      = pk4(a10);
  *(s16x4*)(yl + (16 + l15)*40 + 16 + quad*4) = pk4(a11);
  bf16x8 y0 = *(const bf16x8*)(yl + l15*40 + quad*8);
  bf16x8 y1 = *(const bf16x8*)(yl + (16 + l15)*40 + quad*8);
  bf16x8 wf = ((const bf16x8*)WzF)[ct*64 + lane];
  f32x4 zq0 = MFMA(wf, y0, z4);
  f32x4 zq1 = MFMA(wf, y1, z4);
  int c0 = ct*16 + quad*4;
  f32x4 b2 = *(const f32x4*)(bias2 + c0);
  int q0i = qblk * 32;
  const float* xp0 = x + (b*64 + c0)*4096 + q0i + l15;
  f32x4 s0, s1;
  s0.x = zq0.x + b2.x + xp0[0];
  s0.y = zq0.y + b2.y + xp0[4096];
  s0.z = zq0.z + b2.z + xp0[8192];
  s0.w = zq0.w + b2.w + xp0[12288];
  s1.x = zq1.x + b2.x + xp0[16];
  s1.y = zq1.y + b2.y + xp0[4096 + 16];
  s1.z = zq1.z + b2.z + xp0[8192 + 16];
  s1.w = zq1.w + b2.w + xp0[12288 + 16];
  {
    int q = q0i + l15, h = q >> 6, w = q & 63;
    *(s16x4*)(z_pad + b*ZPB + ((h + 7)*78 + (w + 7))*64 + c0) = pk4(s0);
    q = q0i + 16 + l15; h = q >> 6; w = q & 63;
    *(s16x4*)(z_pad + b*ZPB + ((h + 7)*78 + (w + 7))*64 + c0) = pk4(s1);
  }
  // zmean contribution: sum over the 32 q of this block per channel
  f32x4 zs = s0 + s1;
  #pragma unroll
  for (int m = 1; m < 16; m <<= 1) {
    zs.x += __shfl_xor(zs.x, m);
    zs.y += __shfl_xor(zs.y, m);
    zs.z += __shfl_xor(zs.z, m);
    zs.w += __shfl_xor(zs.w, m);
  }
  if (l15 == 0) {
    atomicAdd(zmean + b*64 + c0 + 0, zs.x);
    atomicAdd(zmean + b*64 + c0 + 1, zs.y);
    atomicAdd(zmean + b*64 + c0 + 2, zs.z);
    atomicAdd(zmean + b*64 + c0 + 3, zs.w);
  }
}

// ========== k_conv: collapsed 28-tap ASPP conv with inlined c_b ==========
__global__ __launch_bounds__(64) void k_conv(
    const unsigned short* __restrict__ z_pad, const unsigned short* __restrict__ Wfrag,
    const float* __restrict__ zmean, const float* __restrict__ am_wT,
    const float* __restrict__ am_b, const float* __restrict__ owT0,
    const float* __restrict__ cbias, float* __restrict__ out) {
  static constexpr int DYt[28] = {0, -3,-3,-3,0,0,0,3,3,3,
                                     -5,-5,-5,0,0,0,5,5,5,
                                     -7,-7,-7,0,0,0,7,7,7};
  static constexpr int DXt[28] = {0, -3,0,3,-3,0,3,-3,0,3,
                                     -5,0,5,-5,0,5,-5,0,5,
                                     -7,0,7,-7,0,7,-7,0,7};
  int blk = blockIdx.x;                       // b(4) x h(64) x dt2(2) x wt2(2)
  int b = blk >> 8, h = (blk >> 2) & 63, dt2 = (blk >> 1) & 1, wt2 = blk & 1;
  int lane = threadIdx.x, quad = lane >> 4, l15 = lane & 15;
  // ---- inlined c_b (independent of main loop; latency hides under MFMAs) ----
  float zml = zmean[b*64 + lane] * (1.f / 4096.f);
  float img = am_b[lane];
  for (int c = 0; c < 64; ++c) img += am_wT[c*64 + lane] * __shfl(zml, c);
  float cbd = cbias[lane];
  for (int dd = 0; dd < 64; ++dd) cbd += owT0[dd*64 + lane] * __shfl(img, dd);
  // ---- main implicit GEMM ----
  const unsigned short* zb = z_pad + b*ZPB + ((h + 7)*78 + 7)*64 + quad*8;
  const bf16x8* wfp = (const bf16x8*)Wfrag + lane;
  int d0 = dt2*2 + 0, d1 = dt2*2 + 1;
  const f32x4 z4 = {0.f, 0.f, 0.f, 0.f};
  f32x4 acc00 = z4, acc01 = z4, acc10 = z4, acc11 = z4;
  int col0 = ((wt2*2 + 0)*16 + l15)*64;
  int col1 = ((wt2*2 + 1)*16 + l15)*64;
  #pragma unroll
  for (int tap = 0; tap < 28; ++tap) {
    int toff = (DYt[tap]*78 + DXt[tap])*64;
    const unsigned short* zrow = zb + toff;
    #pragma unroll
    for (int cc = 0; cc < 2; ++cc) {
      bf16x8 zf0 = *(const bf16x8*)(zrow + col0 + cc*32);
      bf16x8 zf1 = *(const bf16x8*)(zrow + col1 + cc*32);
      bf16x8 wf0 = wfp[((tap*4 + d0)*2 + cc)*64];
      bf16x8 wf1 = wfp[((tap*4 + d1)*2 + cc)*64];
      acc00 = MFMA(wf0, zf0, acc00);
      acc01 = MFMA(wf0, zf1, acc01);
      acc10 = MFMA(wf1, zf0, acc10);
      acc11 = MFMA(wf1, zf1, acc11);
    }
  }
  int dd0 = d0*16 + quad*4, dd1 = d1*16 + quad*4;
  f32x4 cb0v, cb1v;
  cb0v.x = __shfl(cbd, dd0 + 0); cb0v.y = __shfl(cbd, dd0 + 1);
  cb0v.z = __shfl(cbd, dd0 + 2); cb0v.w = __shfl(cbd, dd0 + 3);
  cb1v.x = __shfl(cbd, dd1 + 0); cb1v.y = __shfl(cbd, dd1 + 1);
  cb1v.z = __shfl(cbd, dd1 + 2); cb1v.w = __shfl(cbd, dd1 + 3);
  acc00 += cb0v; acc01 += cb0v; acc10 += cb1v; acc11 += cb1v;
  float* ob = out + b*262144 + h*64;
  int w0 = (wt2*2 + 0)*16 + l15, w1 = (wt2*2 + 1)*16 + l15;
  ob[(dd0 + 0)*4096 + w0] = acc00.x;
  ob[(dd0 + 1)*4096 + w0] = acc00.y;
  ob[(dd0 + 2)*4096 + w0] = acc00.z;
  ob[(dd0 + 3)*4096 + w0] = acc00.w;
  ob[(dd0 + 0)*4096 + w1] = acc01.x;
  ob[(dd0 + 1)*4096 + w1] = acc01.y;
  ob[(dd0 + 2)*4096 + w1] = acc01.z;
  ob[(dd0 + 3)*4096 + w1] = acc01.w;
  ob[(dd1 + 0)*4096 + w0] = acc10.x;
  ob[(dd1 + 1)*4096 + w0] = acc10.y;
  ob[(dd1 + 2)*4096 + w0] = acc10.z;
  ob[(dd1 + 3)*4096 + w0] = acc10.w;
  ob[(dd1 + 0)*4096 + w1] = acc11.x;
  ob[(dd1 + 1)*4096 + w1] = acc11.y;
  ob[(dd1 + 2)*4096 + w1] = acc11.z;
  ob[(dd1 + 3)*4096 + w1] = acc11.w;
}

extern "C" void kernel_launch(void* const* d_in, const int* in_sizes, int n_in,
                              void* d_out, int out_size, void* d_ws, size_t ws_size,
                              hipStream_t stream) {
  const float* x    = (const float*)d_in[0];
  const float* g_w  = (const float*)d_in[1];
  const float* g_b  = (const float*)d_in[2];
  const float* th_w = (const float*)d_in[3];
  const float* th_b = (const float*)d_in[4];
  const float* ph_w = (const float*)d_in[5];
  const float* ph_b = (const float*)d_in[6];
  const float* Wz_w = (const float*)d_in[7];
  const float* Wz_b = (const float*)d_in[8];
  const float* bn_g = (const float*)d_in[9];
  const float* bn_b = (const float*)d_in[10];
  const float* am_w = (const float*)d_in[11];
  const float* am_b = (const float*)d_in[12];
  const float* a1_w = (const float*)d_in[13];
  const float* a1_b = (const float*)d_in[14];
  const float* a3_w = (const float*)d_in[15];
  const float* a3_b = (const float*)d_in[16];
  const float* a5_w = (const float*)d_in[17];
  const float* a5_b = (const float*)d_in[18];
  const float* a7_w = (const float*)d_in[19];
  const float* a7_b = (const float*)d_in[20];
  const float* out_w = (const float*)d_in[21];
  const float* out_b = (const float*)d_in[22];
  float* out = (float*)d_out;
  char* ws = (char*)d_ws;
  unsigned short* thetaB = (unsigned short*)(ws + 0);
  unsigned short* phiB   = (unsigned short*)(ws + 1048576);
  unsigned short* gB     = (unsigned short*)(ws + 2097152);
  unsigned short* z_pad  = (unsigned short*)(ws + 3145728);
  unsigned short* Wfrag  = (unsigned short*)(ws + 6260736);
  unsigned short* WzF    = (unsigned short*)(ws + 6490112);
  float* zmean           = (float*)(ws + 6494208);
  float* bias2           = (float*)(ws + 6495232);
  float* am_wT           = (float*)(ws + 6495488);
  float* owT0            = (float*)(ws + 6511872);
  float* cbias           = (float*)(ws + 6528256);

  k_setup<<<dim3(1220), dim3(256), 0, stream>>>(
      x, th_w, th_b, ph_w, ph_b, g_w, g_b, out_w, out_b,
      a1_w, a3_w, a5_w, a7_w, a1_b, a3_b, a5_b, a7_b,
      Wz_w, Wz_b, bn_g, bn_b, am_w,
      (unsigned*)z_pad, zmean, Wfrag, WzF, bias2,
      thetaB, phiB, gB, am_wT, owT0, cbias);
  k_attn<<<dim3(512), dim3(512), 0, stream>>>(thetaB, phiB, gB, WzF, bias2, x,
                                              z_pad, zmean);
  k_conv<<<dim3(1024), dim3(64), 0, stream>>>(z_pad, Wfrag, zmean, am_wT, am_b,
                                              owT0, cbias, out);
}